// Round 2
// baseline (1933.443 us; speedup 1.0000x reference)
//
#include <hip/hip_runtime.h>

#define LEN_TOT 10200
#define BB 2
#define DD 256
#define NHH 8
#define NLL 4
#define NPP 4
#define DHH 32
#define DFF_ 1024
#define ROWS (BB * LEN_TOT)   // 20400

// ---------------------------------------------------------------- ref points
__global__ __launch_bounds__(256) void ref_points_kernel(
    const float* __restrict__ vr,   // (B, NL, 2)
    float* __restrict__ ref)        // (B*LEN, NL, 2)
{
    int i = blockIdx.x * blockDim.x + threadIdx.x;
    if (i >= BB * LEN_TOT) return;
    int b = i / LEN_TOT, pos = i % LEN_TOT;
    int lvl, st, Hl, Wl;
    if (pos < 7680)      { lvl = 0; st = 0;     Hl = 48; Wl = 160; }
    else if (pos < 9600) { lvl = 1; st = 7680;  Hl = 24; Wl = 80;  }
    else if (pos < 10080){ lvl = 2; st = 9600;  Hl = 12; Wl = 40;  }
    else                 { lvl = 3; st = 10080; Hl = 6;  Wl = 20;  }
    int local = pos - st;
    int row = local / Wl, col = local % Wl;
    float rx = (col + 0.5f) / (vr[(b * NLL + lvl) * 2 + 0] * (float)Wl);
    float ry = (row + 0.5f) / (vr[(b * NLL + lvl) * 2 + 1] * (float)Hl);
    #pragma unroll
    for (int ol = 0; ol < NLL; ++ol) {
        ref[((size_t)i * NLL + ol) * 2 + 0] = rx * vr[(b * NLL + ol) * 2 + 0];
        ref[((size_t)i * NLL + ol) * 2 + 1] = ry * vr[(b * NLL + ol) * 2 + 1];
    }
}

// ---------------------------------------------------------------- elementwise
__global__ __launch_bounds__(256) void add_kernel(
    const float* __restrict__ a, const float* __restrict__ b,
    float* __restrict__ c, int n4)
{
    int i = blockIdx.x * blockDim.x + threadIdx.x;
    if (i >= n4) return;
    float4 va = ((const float4*)a)[i];
    float4 vb = ((const float4*)b)[i];
    float4 vc;
    vc.x = va.x + vb.x; vc.y = va.y + vb.y; vc.z = va.z + vb.z; vc.w = va.w + vb.w;
    ((float4*)c)[i] = vc;
}

// ---------------------------------------------------------------- softmax-16
__global__ __launch_bounds__(256) void softmax16_kernel(float* __restrict__ attn)
{
    int i = blockIdx.x * blockDim.x + threadIdx.x;   // over ROWS*NH
    if (i >= ROWS * NHH) return;
    float* p = attn + (size_t)i * 16;
    float v[16];
    float m = -1e30f;
    #pragma unroll
    for (int j = 0; j < 16; ++j) { v[j] = p[j]; m = fmaxf(m, v[j]); }
    float s = 0.f;
    #pragma unroll
    for (int j = 0; j < 16; ++j) { v[j] = __expf(v[j] - m); s += v[j]; }
    float inv = 1.f / s;
    #pragma unroll
    for (int j = 0; j < 16; ++j) p[j] = v[j] * inv;
}

// ---------------------------------------------------------------- fp32 GEMM
template<bool RELU>
__global__ __launch_bounds__(256) void gemm_kernel(
    const float* __restrict__ A, const float* __restrict__ W,
    const float* __restrict__ bias, float* __restrict__ C,
    int M, int N, int K)
{
    __shared__ float As[16][64];
    __shared__ float Ws[16][64];
    int tid = threadIdx.x;
    int tx = tid & 15, ty = tid >> 4;
    int rowBase = blockIdx.x * 64;
    int colBase = blockIdx.y * 64;

    int arow  = tid >> 2;          // 0..63
    int akcol = (tid & 3) << 2;    // 0,4,8,12
    int wk    = tid >> 4;          // 0..15
    int wn    = (tid & 15) << 2;   // 0..60

    float acc[4][4];
    #pragma unroll
    for (int i = 0; i < 4; ++i)
        #pragma unroll
        for (int j = 0; j < 4; ++j) acc[i][j] = 0.f;

    for (int k0 = 0; k0 < K; k0 += 16) {
        float4 av = make_float4(0.f, 0.f, 0.f, 0.f);
        if (rowBase + arow < M)
            av = *(const float4*)(A + (size_t)(rowBase + arow) * K + k0 + akcol);
        float4 wv = *(const float4*)(W + (size_t)(k0 + wk) * N + colBase + wn);
        As[akcol + 0][arow] = av.x;
        As[akcol + 1][arow] = av.y;
        As[akcol + 2][arow] = av.z;
        As[akcol + 3][arow] = av.w;
        *(float4*)&Ws[wk][wn] = wv;
        __syncthreads();
        #pragma unroll
        for (int k = 0; k < 16; ++k) {
            float4 a = *(float4*)&As[k][ty << 2];
            float4 w = *(float4*)&Ws[k][tx << 2];
            float aa[4] = {a.x, a.y, a.z, a.w};
            float ww[4] = {w.x, w.y, w.z, w.w};
            #pragma unroll
            for (int i = 0; i < 4; ++i)
                #pragma unroll
                for (int j = 0; j < 4; ++j)
                    acc[i][j] = fmaf(aa[i], ww[j], acc[i][j]);
        }
        __syncthreads();
    }

    float4 bs = *(const float4*)(bias + colBase + (tx << 2));
    float bb[4] = {bs.x, bs.y, bs.z, bs.w};
    #pragma unroll
    for (int i = 0; i < 4; ++i) {
        int r = rowBase + (ty << 2) + i;
        if (r < M) {
            float4 o;
            o.x = acc[i][0] + bb[0];
            o.y = acc[i][1] + bb[1];
            o.z = acc[i][2] + bb[2];
            o.w = acc[i][3] + bb[3];
            if (RELU) {
                o.x = fmaxf(o.x, 0.f); o.y = fmaxf(o.y, 0.f);
                o.z = fmaxf(o.z, 0.f); o.w = fmaxf(o.w, 0.f);
            }
            *(float4*)(C + (size_t)r * N + colBase + (tx << 2)) = o;
        }
    }
}

// ---------------------------------------------------------------- sampling
__global__ __launch_bounds__(256) void sample_kernel(
    const float* __restrict__ val,   // (B, LEN, NH, DH)
    const float* __restrict__ offs,  // (B*Lq, NH, NL, NP, 2)
    const float* __restrict__ attn,  // (B*Lq, NH, 16)
    const float* __restrict__ ref,   // (B*Lq, NL, 2)
    float* __restrict__ out)         // (B*Lq, NH, DH)
{
    constexpr int HLs[4] = {48, 24, 12, 6};
    constexpr int WLs[4] = {160, 80, 40, 20};
    constexpr int STs[4] = {0, 7680, 9600, 10080};

    int item = blockIdx.x * 8 + (threadIdx.x >> 5);  // (b*Lq)*NH + h
    int c = threadIdx.x & 31;
    if (item >= ROWS * NHH) return;
    int h  = item & (NHH - 1);
    int bq = item >> 3;               // b*Lq + q
    int b  = bq / LEN_TOT;

    const float* offp = offs + (size_t)item * (NLL * NPP * 2);
    const float* attp = attn + (size_t)item * 16;
    const float* refp = ref + (size_t)bq * (NLL * 2);

    float acc = 0.f;
    #pragma unroll
    for (int lvl = 0; lvl < NLL; ++lvl) {
        const int Hl = HLs[lvl], Wl = WLs[lvl];
        float rx = refp[lvl * 2 + 0];
        float ry = refp[lvl * 2 + 1];
        const float* vbase =
            val + ((size_t)(b * LEN_TOT + STs[lvl]) * NHH + h) * DHH + c;
        #pragma unroll
        for (int p = 0; p < NPP; ++p) {
            float a = attp[lvl * NPP + p];
            float x = rx * (float)Wl + offp[(lvl * NPP + p) * 2 + 0] - 0.5f;
            float y = ry * (float)Hl + offp[(lvl * NPP + p) * 2 + 1] - 0.5f;
            float xf = floorf(x), yf = floorf(y);
            float fx = x - xf, fy = y - yf;
            int x0 = (int)xf, y0 = (int)yf;
            #pragma unroll
            for (int dy = 0; dy < 2; ++dy) {
                #pragma unroll
                for (int dx = 0; dx < 2; ++dx) {
                    int xi = x0 + dx, yi = y0 + dy;
                    float w = (dx ? fx : 1.f - fx) * (dy ? fy : 1.f - fy);
                    bool valid = (xi >= 0) & (xi < Wl) & (yi >= 0) & (yi < Hl);
                    int xc = min(max(xi, 0), Wl - 1);
                    int yc = min(max(yi, 0), Hl - 1);
                    float v = vbase[(size_t)(yc * Wl + xc) * (NHH * DHH)];
                    acc = fmaf(a * (valid ? w : 0.f), v, acc);
                }
            }
        }
    }
    out[(size_t)item * DHH + c] = acc;
}

// ---------------------------------------------------------------- residual+LN
__global__ __launch_bounds__(256) void resln_kernel(
    float* __restrict__ x, const float* __restrict__ r,
    const float* __restrict__ g, const float* __restrict__ bta)
{
    int row = blockIdx.x * 4 + (threadIdx.x >> 6);
    int lane = threadIdx.x & 63;
    if (row >= ROWS) return;
    float4 v  = *(const float4*)(x + (size_t)row * DD + lane * 4);
    float4 rr = *(const float4*)(r + (size_t)row * DD + lane * 4);
    v.x += rr.x; v.y += rr.y; v.z += rr.z; v.w += rr.w;
    float s  = v.x + v.y + v.z + v.w;
    float s2 = v.x * v.x + v.y * v.y + v.z * v.z + v.w * v.w;
    #pragma unroll
    for (int o = 1; o < 64; o <<= 1) {
        s  += __shfl_xor(s, o);
        s2 += __shfl_xor(s2, o);
    }
    float mean = s * (1.f / DD);
    float var  = s2 * (1.f / DD) - mean * mean;
    float inv  = rsqrtf(var + 1e-5f);
    float4 gg = *(const float4*)(g + lane * 4);
    float4 bb = *(const float4*)(bta + lane * 4);
    float4 o;
    o.x = (v.x - mean) * inv * gg.x + bb.x;
    o.y = (v.y - mean) * inv * gg.y + bb.y;
    o.z = (v.z - mean) * inv * gg.z + bb.z;
    o.w = (v.w - mean) * inv * gg.w + bb.w;
    *(float4*)(x + (size_t)row * DD + lane * 4) = o;
}

// ---------------------------------------------------------------- launch
extern "C" void kernel_launch(void* const* d_in, const int* in_sizes, int n_in,
                              void* d_out, int out_size, void* d_ws, size_t ws_size,
                              hipStream_t stream)
{
    const float* src    = (const float*)d_in[0];
    const float* pos    = (const float*)d_in[1];
    const float* vr     = (const float*)d_in[2];
    const float* W_off  = (const float*)d_in[3];
    const float* b_off  = (const float*)d_in[4];
    const float* W_attn = (const float*)d_in[5];
    const float* b_attn = (const float*)d_in[6];
    const float* W_val  = (const float*)d_in[7];
    const float* b_val  = (const float*)d_in[8];
    const float* W_out  = (const float*)d_in[9];
    const float* b_out  = (const float*)d_in[10];
    const float* ln1_g  = (const float*)d_in[11];
    const float* ln1_b  = (const float*)d_in[12];
    const float* W_ff1  = (const float*)d_in[13];
    const float* b_ff1  = (const float*)d_in[14];
    const float* W_ff2  = (const float*)d_in[15];
    const float* b_ff2  = (const float*)d_in[16];
    const float* ln2_g  = (const float*)d_in[17];
    const float* ln2_b  = (const float*)d_in[18];

    float* x = (float*)d_out;

    float* ws = (float*)d_ws;
    size_t o = 0;
    float* q    = ws + o; o += (size_t)ROWS * DD;      // reused as att_out / ff_out
    float* offs = ws + o; o += (size_t)ROWS * DD;
    float* attn = ws + o; o += (size_t)ROWS * 128;
    float* val  = ws + o; o += (size_t)ROWS * DD;
    float* samp = ws + o; o += (size_t)ROWS * DD;
    float* h    = ws + o; o += (size_t)ROWS * DFF_;
    float* ref  = ws + o; o += (size_t)ROWS * NLL * 2;

    hipMemcpyAsync(x, src, sizeof(float) * (size_t)ROWS * DD,
                   hipMemcpyDeviceToDevice, stream);

    ref_points_kernel<<<(ROWS + 255) / 256, 256, 0, stream>>>(vr, ref);

    const int n4 = ROWS * DD / 4;
    dim3 gN256((ROWS + 63) / 64, 256 / 64);
    dim3 gN128((ROWS + 63) / 64, 128 / 64);
    dim3 gN1024((ROWS + 63) / 64, DFF_ / 64);

    for (int l = 0; l < 3; ++l) {
        // q = x + pos
        add_kernel<<<(n4 + 255) / 256, 256, 0, stream>>>(x, pos, q, n4);
        // offs = q @ W_off + b_off
        gemm_kernel<false><<<gN256, 256, 0, stream>>>(
            q, W_off + (size_t)l * DD * 256, b_off + (size_t)l * 256, offs,
            ROWS, 256, DD);
        // attn = softmax16(q @ W_attn + b_attn)
        gemm_kernel<false><<<gN128, 256, 0, stream>>>(
            q, W_attn + (size_t)l * DD * 128, b_attn + (size_t)l * 128, attn,
            ROWS, 128, DD);
        softmax16_kernel<<<(ROWS * NHH + 255) / 256, 256, 0, stream>>>(attn);
        // val = x @ W_val + b_val
        gemm_kernel<false><<<gN256, 256, 0, stream>>>(
            x, W_val + (size_t)l * DD * DD, b_val + (size_t)l * DD, val,
            ROWS, 256, DD);
        // deformable sampling
        sample_kernel<<<(ROWS * NHH + 7) / 8, 256, 0, stream>>>(
            val, offs, attn, ref, samp);
        // att_out = samp @ W_out + b_out  (into q buffer)
        gemm_kernel<false><<<gN256, 256, 0, stream>>>(
            samp, W_out + (size_t)l * DD * DD, b_out + (size_t)l * DD, q,
            ROWS, 256, DD);
        // x = LN(x + att_out)
        resln_kernel<<<(ROWS + 3) / 4, 256, 0, stream>>>(
            x, q, ln1_g + (size_t)l * DD, ln1_b + (size_t)l * DD);
        // h = relu(x @ W_ff1 + b_ff1)
        gemm_kernel<true><<<gN1024, 256, 0, stream>>>(
            x, W_ff1 + (size_t)l * DD * DFF_, b_ff1 + (size_t)l * DFF_, h,
            ROWS, DFF_, DD);
        // ff = h @ W_ff2 + b_ff2 (into q buffer)
        gemm_kernel<false><<<gN256, 256, 0, stream>>>(
            h, W_ff2 + (size_t)l * DFF_ * DD, b_ff2 + (size_t)l * DD, q,
            ROWS, 256, DFF_);
        // x = LN(x + ff)
        resln_kernel<<<(ROWS + 3) / 4, 256, 0, stream>>>(
            x, q, ln2_g + (size_t)l * DD, ln2_b + (size_t)l * DD);
    }
}

// Round 3
// 905.462 us; speedup vs baseline: 2.1353x; 2.1353x over previous
//
#include <hip/hip_runtime.h>

typedef short bf16x8 __attribute__((ext_vector_type(8)));
typedef float f32x4  __attribute__((ext_vector_type(4)));

#define LEN_TOT 10200
#define BB 2
#define DD 256
#define NHH 8
#define NLL 4
#define NPP 4
#define DHH 32
#define DFF_ 1024
#define ROWS (BB * LEN_TOT)   // 20400

__device__ inline unsigned short f2bf(float f) {
    unsigned int u = __float_as_uint(f);
    u += 0x7fffu + ((u >> 16) & 1u);     // RNE
    return (unsigned short)(u >> 16);
}
__device__ inline unsigned int pack2(float a, float b) {
    return (unsigned int)f2bf(a) | ((unsigned int)f2bf(b) << 16);
}

// ---------------------------------------------------------------- ref points
__global__ __launch_bounds__(256) void ref_points_kernel(
    const float* __restrict__ vr, float* __restrict__ ref)
{
    int i = blockIdx.x * blockDim.x + threadIdx.x;
    if (i >= BB * LEN_TOT) return;
    int b = i / LEN_TOT, pos = i % LEN_TOT;
    int lvl, st, Hl, Wl;
    if (pos < 7680)      { lvl = 0; st = 0;     Hl = 48; Wl = 160; }
    else if (pos < 9600) { lvl = 1; st = 7680;  Hl = 24; Wl = 80;  }
    else if (pos < 10080){ lvl = 2; st = 9600;  Hl = 12; Wl = 40;  }
    else                 { lvl = 3; st = 10080; Hl = 6;  Wl = 20;  }
    int local = pos - st;
    int row = local / Wl, col = local % Wl;
    float rx = (col + 0.5f) / (vr[(b * NLL + lvl) * 2 + 0] * (float)Wl);
    float ry = (row + 0.5f) / (vr[(b * NLL + lvl) * 2 + 1] * (float)Hl);
    #pragma unroll
    for (int ol = 0; ol < NLL; ++ol) {
        ref[((size_t)i * NLL + ol) * 2 + 0] = rx * vr[(b * NLL + ol) * 2 + 0];
        ref[((size_t)i * NLL + ol) * 2 + 1] = ry * vr[(b * NLL + ol) * 2 + 1];
    }
}

// ---------------------------------------------------------------- src -> x fp32 + x bf16
__global__ __launch_bounds__(256) void convert_src_kernel(
    const float* __restrict__ src, float* __restrict__ x,
    unsigned short* __restrict__ xb, int n8)
{
    int i = blockIdx.x * blockDim.x + threadIdx.x;
    if (i >= n8) return;
    float4 a = ((const float4*)src)[2 * i];
    float4 b = ((const float4*)src)[2 * i + 1];
    ((float4*)x)[2 * i]     = a;
    ((float4*)x)[2 * i + 1] = b;
    uint4 o;
    o.x = pack2(a.x, a.y); o.y = pack2(a.z, a.w);
    o.z = pack2(b.x, b.y); o.w = pack2(b.z, b.w);
    ((uint4*)xb)[i] = o;
}

// ---------------------------------------------------------------- q = bf16(x+pos)
__global__ __launch_bounds__(256) void addq_kernel(
    const float* __restrict__ x, const float* __restrict__ p,
    unsigned short* __restrict__ qb, int n8)
{
    int i = blockIdx.x * blockDim.x + threadIdx.x;
    if (i >= n8) return;
    float4 a0 = ((const float4*)x)[2 * i];
    float4 a1 = ((const float4*)x)[2 * i + 1];
    float4 b0 = ((const float4*)p)[2 * i];
    float4 b1 = ((const float4*)p)[2 * i + 1];
    uint4 o;
    o.x = pack2(a0.x + b0.x, a0.y + b0.y);
    o.y = pack2(a0.z + b0.z, a0.w + b0.w);
    o.z = pack2(a1.x + b1.x, a1.y + b1.y);
    o.w = pack2(a1.z + b1.z, a1.w + b1.w);
    ((uint4*)qb)[i] = o;
}

// ---------------------------------------------------------------- weight transpose fp32[K][N] -> bf16[N][K]
__global__ __launch_bounds__(256) void wt_kernel(
    const float* __restrict__ W, unsigned short* __restrict__ WT, int K, int N)
{
    __shared__ float t[32][33];
    const float* Wl = W + (size_t)blockIdx.z * K * N;
    unsigned short* WTl = WT + (size_t)blockIdx.z * K * N;
    int kb = blockIdx.x * 32, nb = blockIdx.y * 32;
    int tx = threadIdx.x, ty = threadIdx.y;   // 32 x 8
    #pragma unroll
    for (int i = 0; i < 4; ++i)
        t[ty + i * 8][tx] = Wl[(size_t)(kb + ty + i * 8) * N + nb + tx];
    __syncthreads();
    #pragma unroll
    for (int i = 0; i < 4; ++i)
        WTl[(size_t)(nb + ty + i * 8) * K + kb + tx] = f2bf(t[tx][ty + i * 8]);
}

// ---------------------------------------------------------------- softmax-16
__global__ __launch_bounds__(256) void softmax16_kernel(float* __restrict__ attn)
{
    int i = blockIdx.x * blockDim.x + threadIdx.x;
    if (i >= ROWS * NHH) return;
    float* p = attn + (size_t)i * 16;
    float v[16];
    float m = -1e30f;
    #pragma unroll
    for (int j = 0; j < 16; ++j) { v[j] = p[j]; m = fmaxf(m, v[j]); }
    float s = 0.f;
    #pragma unroll
    for (int j = 0; j < 16; ++j) { v[j] = __expf(v[j] - m); s += v[j]; }
    float inv = 1.f / s;
    #pragma unroll
    for (int j = 0; j < 16; ++j) p[j] = v[j] * inv;
}

// ---------------------------------------------------------------- bf16 MFMA GEMM
// C[M,N] = A[M,K](bf16) @ (BT[N,K](bf16))^T + bias.  OUTMODE 0: fp32 out; 1: relu->bf16 out.
// 128x128 tile, BK=64, 4 waves each 64x64. LDS [outer][k] with slot^=(row&7) XOR swizzle.
template<int OUTMODE>
__global__ __launch_bounds__(256) void gemm_bf16(
    const unsigned short* __restrict__ A,
    const unsigned short* __restrict__ BT,
    const float* __restrict__ bias,
    void* __restrict__ Cout,
    int M, int N, int K)
{
    __shared__ short lds[2 * 128 * 64];   // A tile then B tile, bf16
    const int tid = threadIdx.x;
    const int l   = tid & 63;
    const int wid = tid >> 6;
    const int wm  = wid >> 1, wn = wid & 1;
    const int lrow = l & 15, lkg = l >> 4;
    const int rowBase = blockIdx.x * 128;
    const int colBase = blockIdx.y * 128;

    const int srow  = tid >> 3;   // 0..31
    const int sslot = tid & 7;    // 0..7

    f32x4 acc[4][4] = {};

    for (int k0 = 0; k0 < K; k0 += 64) {
        #pragma unroll
        for (int rr = 0; rr < 128; rr += 32) {
            int r = rr + srow;
            int sw = (sslot ^ (r & 7)) * 8;
            int gr = rowBase + r; if (gr > M - 1) gr = M - 1;
            uint4 av = *(const uint4*)(A + (size_t)gr * K + k0 + sslot * 8);
            *(uint4*)&lds[r * 64 + sw] = av;
            int n = colBase + r;
            uint4 bv = *(const uint4*)(BT + (size_t)n * K + k0 + sslot * 8);
            *(uint4*)&lds[8192 + r * 64 + sw] = bv;
        }
        __syncthreads();
        #pragma unroll
        for (int kk = 0; kk < 2; ++kk) {
            int kslot = kk * 4 + lkg;
            int ssw = (kslot ^ (lrow & 7)) * 8;
            bf16x8 af[4], bfr[4];
            #pragma unroll
            for (int mi = 0; mi < 4; ++mi)
                af[mi] = *(const bf16x8*)&lds[(wm * 64 + mi * 16 + lrow) * 64 + ssw];
            #pragma unroll
            for (int ni = 0; ni < 4; ++ni)
                bfr[ni] = *(const bf16x8*)&lds[8192 + (wn * 64 + ni * 16 + lrow) * 64 + ssw];
            #pragma unroll
            for (int mi = 0; mi < 4; ++mi)
                #pragma unroll
                for (int ni = 0; ni < 4; ++ni)
                    acc[mi][ni] = __builtin_amdgcn_mfma_f32_16x16x32_bf16(
                        af[mi], bfr[ni], acc[mi][ni], 0, 0, 0);
        }
        __syncthreads();
    }

    #pragma unroll
    for (int ni = 0; ni < 4; ++ni) {
        int col = colBase + wn * 64 + ni * 16 + lrow;
        float bv = bias[col];
        #pragma unroll
        for (int mi = 0; mi < 4; ++mi) {
            int r0 = rowBase + wm * 64 + mi * 16 + lkg * 4;
            #pragma unroll
            for (int j = 0; j < 4; ++j) {
                int r = r0 + j;
                if (r < M) {
                    float v = acc[mi][ni][j] + bv;
                    if (OUTMODE == 1) {
                        v = fmaxf(v, 0.f);
                        ((unsigned short*)Cout)[(size_t)r * N + col] = f2bf(v);
                    } else {
                        ((float*)Cout)[(size_t)r * N + col] = v;
                    }
                }
            }
        }
    }
}

// ---------------------------------------------------------------- sampling (bf16 out)
__global__ __launch_bounds__(256) void sample_kernel(
    const float* __restrict__ val,   // (B, LEN, NH, DH) fp32
    const float* __restrict__ offs,  // (B*Lq, NH, NL, NP, 2)
    const float* __restrict__ attn,  // (B*Lq, NH, 16)
    const float* __restrict__ ref,   // (B*Lq, NL, 2)
    unsigned short* __restrict__ out)// (B*Lq, NH, DH) bf16
{
    constexpr int HLs[4] = {48, 24, 12, 6};
    constexpr int WLs[4] = {160, 80, 40, 20};
    constexpr int STs[4] = {0, 7680, 9600, 10080};

    int item = blockIdx.x * 8 + (threadIdx.x >> 5);
    int c = threadIdx.x & 31;
    if (item >= ROWS * NHH) return;
    int h  = item & (NHH - 1);
    int bq = item >> 3;
    int b  = bq / LEN_TOT;

    const float* offp = offs + (size_t)item * (NLL * NPP * 2);
    const float* attp = attn + (size_t)item * 16;
    const float* refp = ref + (size_t)bq * (NLL * 2);

    float acc = 0.f;
    #pragma unroll
    for (int lvl = 0; lvl < NLL; ++lvl) {
        const int Hl = HLs[lvl], Wl = WLs[lvl];
        float rx = refp[lvl * 2 + 0];
        float ry = refp[lvl * 2 + 1];
        const float* vbase =
            val + ((size_t)(b * LEN_TOT + STs[lvl]) * NHH + h) * DHH + c;
        #pragma unroll
        for (int p = 0; p < NPP; ++p) {
            float a = attp[lvl * NPP + p];
            float x = rx * (float)Wl + offp[(lvl * NPP + p) * 2 + 0] - 0.5f;
            float y = ry * (float)Hl + offp[(lvl * NPP + p) * 2 + 1] - 0.5f;
            float xf = floorf(x), yf = floorf(y);
            float fx = x - xf, fy = y - yf;
            int x0 = (int)xf, y0 = (int)yf;
            #pragma unroll
            for (int dy = 0; dy < 2; ++dy) {
                #pragma unroll
                for (int dx = 0; dx < 2; ++dx) {
                    int xi = x0 + dx, yi = y0 + dy;
                    float w = (dx ? fx : 1.f - fx) * (dy ? fy : 1.f - fy);
                    bool valid = (xi >= 0) & (xi < Wl) & (yi >= 0) & (yi < Hl);
                    int xc = min(max(xi, 0), Wl - 1);
                    int yc = min(max(yi, 0), Hl - 1);
                    float v = vbase[(size_t)(yc * Wl + xc) * (NHH * DHH)];
                    acc = fmaf(a * (valid ? w : 0.f), v, acc);
                }
            }
        }
    }
    out[(size_t)item * DHH + c] = f2bf(acc);
}

// ---------------------------------------------------------------- residual + LN (+ bf16 copy)
__global__ __launch_bounds__(256) void resln_kernel(
    float* __restrict__ x, const float* __restrict__ r,
    const float* __restrict__ g, const float* __restrict__ bta,
    unsigned short* __restrict__ xb)
{
    int row = blockIdx.x * 4 + (threadIdx.x >> 6);
    int lane = threadIdx.x & 63;
    if (row >= ROWS) return;
    float4 v  = *(const float4*)(x + (size_t)row * DD + lane * 4);
    float4 rr = *(const float4*)(r + (size_t)row * DD + lane * 4);
    v.x += rr.x; v.y += rr.y; v.z += rr.z; v.w += rr.w;
    float s  = v.x + v.y + v.z + v.w;
    float s2 = v.x * v.x + v.y * v.y + v.z * v.z + v.w * v.w;
    #pragma unroll
    for (int o = 1; o < 64; o <<= 1) {
        s  += __shfl_xor(s, o);
        s2 += __shfl_xor(s2, o);
    }
    float mean = s * (1.f / DD);
    float var  = s2 * (1.f / DD) - mean * mean;
    float inv  = rsqrtf(var + 1e-5f);
    float4 gg = *(const float4*)(g + lane * 4);
    float4 bb = *(const float4*)(bta + lane * 4);
    float4 o;
    o.x = (v.x - mean) * inv * gg.x + bb.x;
    o.y = (v.y - mean) * inv * gg.y + bb.y;
    o.z = (v.z - mean) * inv * gg.z + bb.z;
    o.w = (v.w - mean) * inv * gg.w + bb.w;
    *(float4*)(x + (size_t)row * DD + lane * 4) = o;
    uint2 ob;
    ob.x = pack2(o.x, o.y);
    ob.y = pack2(o.z, o.w);
    ((uint2*)(xb + (size_t)row * DD))[lane] = ob;
}

// ---------------------------------------------------------------- launch
extern "C" void kernel_launch(void* const* d_in, const int* in_sizes, int n_in,
                              void* d_out, int out_size, void* d_ws, size_t ws_size,
                              hipStream_t stream)
{
    const float* src    = (const float*)d_in[0];
    const float* pos    = (const float*)d_in[1];
    const float* vr     = (const float*)d_in[2];
    const float* W_off  = (const float*)d_in[3];
    const float* b_off  = (const float*)d_in[4];
    const float* W_attn = (const float*)d_in[5];
    const float* b_attn = (const float*)d_in[6];
    const float* W_val  = (const float*)d_in[7];
    const float* b_val  = (const float*)d_in[8];
    const float* W_out  = (const float*)d_in[9];
    const float* b_out  = (const float*)d_in[10];
    const float* ln1_g  = (const float*)d_in[11];
    const float* ln1_b  = (const float*)d_in[12];
    const float* W_ff1  = (const float*)d_in[13];
    const float* b_ff1  = (const float*)d_in[14];
    const float* W_ff2  = (const float*)d_in[15];
    const float* b_ff2  = (const float*)d_in[16];
    const float* ln2_g  = (const float*)d_in[17];
    const float* ln2_b  = (const float*)d_in[18];

    float* x = (float*)d_out;
    float* ws = (float*)d_ws;
    size_t o = 0;
    float* offs = ws + o; o += (size_t)ROWS * 256;
    float* attn = ws + o; o += (size_t)ROWS * 128;
    float* val  = ws + o; o += (size_t)ROWS * 256;
    float* tmp  = ws + o; o += (size_t)ROWS * 256;
    float* ref  = ws + o; o += (size_t)ROWS * 8;

    unsigned short* ub = (unsigned short*)(ws + o);
    size_t uo = 0;
    unsigned short* q_bf    = ub + uo; uo += (size_t)ROWS * 256;
    unsigned short* x_bf    = ub + uo; uo += (size_t)ROWS * 256;
    unsigned short* samp_bf = ub + uo; uo += (size_t)ROWS * 256;
    unsigned short* h_bf    = ub + uo; uo += (size_t)ROWS * DFF_;
    unsigned short* WT_off  = ub + uo; uo += (size_t)3 * 256 * 256;
    unsigned short* WT_attn = ub + uo; uo += (size_t)3 * 256 * 128;
    unsigned short* WT_val  = ub + uo; uo += (size_t)3 * 256 * 256;
    unsigned short* WT_out  = ub + uo; uo += (size_t)3 * 256 * 256;
    unsigned short* WT_ff1  = ub + uo; uo += (size_t)3 * 256 * 1024;
    unsigned short* WT_ff2  = ub + uo; uo += (size_t)3 * 1024 * 256;

    const int n8 = ROWS * DD / 8;

    convert_src_kernel<<<(n8 + 255) / 256, 256, 0, stream>>>(src, x, x_bf, n8);
    ref_points_kernel<<<(ROWS + 255) / 256, 256, 0, stream>>>(vr, ref);

    dim3 wtb(32, 8);
    wt_kernel<<<dim3(8,  8, 3), wtb, 0, stream>>>(W_off,  WT_off,  256, 256);
    wt_kernel<<<dim3(8,  4, 3), wtb, 0, stream>>>(W_attn, WT_attn, 256, 128);
    wt_kernel<<<dim3(8,  8, 3), wtb, 0, stream>>>(W_val,  WT_val,  256, 256);
    wt_kernel<<<dim3(8,  8, 3), wtb, 0, stream>>>(W_out,  WT_out,  256, 256);
    wt_kernel<<<dim3(8, 32, 3), wtb, 0, stream>>>(W_ff1,  WT_ff1,  256, 1024);
    wt_kernel<<<dim3(32, 8, 3), wtb, 0, stream>>>(W_ff2,  WT_ff2,  1024, 256);

    dim3 g256(160, 2), g128(160, 1), g1024(160, 8);

    for (int l = 0; l < 3; ++l) {
        addq_kernel<<<(n8 + 255) / 256, 256, 0, stream>>>(x, pos, q_bf, n8);
        gemm_bf16<0><<<g256, 256, 0, stream>>>(
            q_bf, WT_off + (size_t)l * 65536, b_off + (size_t)l * 256, offs,
            ROWS, 256, 256);
        gemm_bf16<0><<<g128, 256, 0, stream>>>(
            q_bf, WT_attn + (size_t)l * 32768, b_attn + (size_t)l * 128, attn,
            ROWS, 128, 256);
        softmax16_kernel<<<(ROWS * NHH + 255) / 256, 256, 0, stream>>>(attn);
        gemm_bf16<0><<<g256, 256, 0, stream>>>(
            x_bf, WT_val + (size_t)l * 65536, b_val + (size_t)l * 256, val,
            ROWS, 256, 256);
        sample_kernel<<<(ROWS * NHH + 7) / 8, 256, 0, stream>>>(
            val, offs, attn, ref, samp_bf);
        gemm_bf16<0><<<g256, 256, 0, stream>>>(
            samp_bf, WT_out + (size_t)l * 65536, b_out + (size_t)l * 256, tmp,
            ROWS, 256, 256);
        resln_kernel<<<(ROWS + 3) / 4, 256, 0, stream>>>(
            x, tmp, ln1_g + (size_t)l * 256, ln1_b + (size_t)l * 256, x_bf);
        gemm_bf16<1><<<g1024, 256, 0, stream>>>(
            x_bf, WT_ff1 + (size_t)l * 262144, b_ff1 + (size_t)l * 1024, h_bf,
            ROWS, 1024, 256);
        gemm_bf16<0><<<g256, 256, 0, stream>>>(
            h_bf, WT_ff2 + (size_t)l * 262144, b_ff2 + (size_t)l * 256, tmp,
            ROWS, 256, 1024);
        resln_kernel<<<(ROWS + 3) / 4, 256, 0, stream>>>(
            x, tmp, ln2_g + (size_t)l * 256, ln2_b + (size_t)l * 256, x_bf);
    }
}

// Round 4
// 730.790 us; speedup vs baseline: 2.6457x; 1.2390x over previous
//
#include <hip/hip_runtime.h>

typedef short bf16x8 __attribute__((ext_vector_type(8)));
typedef float f32x4  __attribute__((ext_vector_type(4)));

#define LEN_TOT 10200
#define BB 2
#define DD 256
#define NHH 8
#define NLL 4
#define NPP 4
#define DHH 32
#define DFF_ 1024
#define ROWS (BB * LEN_TOT)   // 20400

__device__ inline unsigned short f2bf(float f) {
    unsigned int u = __float_as_uint(f);
    u += 0x7fffu + ((u >> 16) & 1u);     // RNE
    return (unsigned short)(u >> 16);
}
__device__ inline unsigned int pack2(float a, float b) {
    return (unsigned int)f2bf(a) | ((unsigned int)f2bf(b) << 16);
}

// ---------------------------------------------------------------- ref points
__global__ __launch_bounds__(256) void ref_points_kernel(
    const float* __restrict__ vr, float* __restrict__ ref)
{
    int i = blockIdx.x * blockDim.x + threadIdx.x;
    if (i >= BB * LEN_TOT) return;
    int b = i / LEN_TOT, pos = i % LEN_TOT;
    int lvl, st, Hl, Wl;
    if (pos < 7680)      { lvl = 0; st = 0;     Hl = 48; Wl = 160; }
    else if (pos < 9600) { lvl = 1; st = 7680;  Hl = 24; Wl = 80;  }
    else if (pos < 10080){ lvl = 2; st = 9600;  Hl = 12; Wl = 40;  }
    else                 { lvl = 3; st = 10080; Hl = 6;  Wl = 20;  }
    int local = pos - st;
    int row = local / Wl, col = local % Wl;
    float rx = (col + 0.5f) / (vr[(b * NLL + lvl) * 2 + 0] * (float)Wl);
    float ry = (row + 0.5f) / (vr[(b * NLL + lvl) * 2 + 1] * (float)Hl);
    #pragma unroll
    for (int ol = 0; ol < NLL; ++ol) {
        ref[((size_t)i * NLL + ol) * 2 + 0] = rx * vr[(b * NLL + ol) * 2 + 0];
        ref[((size_t)i * NLL + ol) * 2 + 1] = ry * vr[(b * NLL + ol) * 2 + 1];
    }
}

// ---------------------------------------------------------------- src -> x fp32 + x bf16
__global__ __launch_bounds__(256) void convert_src_kernel(
    const float* __restrict__ src, float* __restrict__ x,
    unsigned short* __restrict__ xb, int n8)
{
    int i = blockIdx.x * blockDim.x + threadIdx.x;
    if (i >= n8) return;
    float4 a = ((const float4*)src)[2 * i];
    float4 b = ((const float4*)src)[2 * i + 1];
    ((float4*)x)[2 * i]     = a;
    ((float4*)x)[2 * i + 1] = b;
    uint4 o;
    o.x = pack2(a.x, a.y); o.y = pack2(a.z, a.w);
    o.z = pack2(b.x, b.y); o.w = pack2(b.z, b.w);
    ((uint4*)xb)[i] = o;
}

// ---------------------------------------------------------------- q = bf16(x+pos)
__global__ __launch_bounds__(256) void addq_kernel(
    const float* __restrict__ x, const float* __restrict__ p,
    unsigned short* __restrict__ qb, int n8)
{
    int i = blockIdx.x * blockDim.x + threadIdx.x;
    if (i >= n8) return;
    float4 a0 = ((const float4*)x)[2 * i];
    float4 a1 = ((const float4*)x)[2 * i + 1];
    float4 b0 = ((const float4*)p)[2 * i];
    float4 b1 = ((const float4*)p)[2 * i + 1];
    uint4 o;
    o.x = pack2(a0.x + b0.x, a0.y + b0.y);
    o.y = pack2(a0.z + b0.z, a0.w + b0.w);
    o.z = pack2(a1.x + b1.x, a1.y + b1.y);
    o.w = pack2(a1.z + b1.z, a1.w + b1.w);
    ((uint4*)qb)[i] = o;
}

// ---------------------------------------------------------------- weight transpose
// fp32 W[K][N] (layer z) -> bf16 WT rows: WT[z*ldOut + (rowOff+n)*K + k]
__global__ __launch_bounds__(256) void wt_kernel(
    const float* __restrict__ W, unsigned short* __restrict__ WT,
    int K, int N, int ldOut, int rowOff)
{
    __shared__ float t[32][33];
    const float* Wl = W + (size_t)blockIdx.z * K * N;
    unsigned short* WTl = WT + (size_t)blockIdx.z * ldOut;
    int kb = blockIdx.x * 32, nb = blockIdx.y * 32;
    int tx = threadIdx.x, ty = threadIdx.y;   // 32 x 8
    #pragma unroll
    for (int i = 0; i < 4; ++i)
        t[ty + i * 8][tx] = Wl[(size_t)(kb + ty + i * 8) * N + nb + tx];
    __syncthreads();
    #pragma unroll
    for (int i = 0; i < 4; ++i)
        WTl[(size_t)(rowOff + nb + ty + i * 8) * K + kb + tx] = f2bf(t[tx][ty + i * 8]);
}

// ---------------------------------------------------------------- bias concat [b_off(256) | b_attn(128)] per layer
__global__ __launch_bounds__(256) void bias_oa_kernel(
    const float* __restrict__ b_off, const float* __restrict__ b_attn,
    float* __restrict__ out)
{
    int i = blockIdx.x * blockDim.x + threadIdx.x;
    if (i >= 3 * 384) return;
    int l = i / 384, j = i % 384;
    out[i] = (j < 256) ? b_off[l * 256 + j] : b_attn[l * 128 + (j - 256)];
}

// ---------------------------------------------------------------- bf16 MFMA GEMM
// C[M,N] = A[M,K](bf16) @ (BT[N,K](bf16))^T + bias.
// OUTMODE 0: fp32 out; 1: relu->bf16; 2: bf16.
// 128x128 tile, BK=64, 4 waves each 64x64. LDS [outer][k], slot^=(row&7) XOR swizzle.
template<int OUTMODE>
__global__ __launch_bounds__(256) void gemm_bf16(
    const unsigned short* __restrict__ A,
    const unsigned short* __restrict__ BT,
    const float* __restrict__ bias,
    void* __restrict__ Cout,
    int M, int N, int K)
{
    __shared__ short lds[2 * 128 * 64];
    const int tid = threadIdx.x;
    const int l   = tid & 63;
    const int wid = tid >> 6;
    const int wm  = wid >> 1, wn = wid & 1;
    const int lrow = l & 15, lkg = l >> 4;
    const int rowBase = blockIdx.x * 128;
    const int colBase = blockIdx.y * 128;

    const int srow  = tid >> 3;   // 0..31
    const int sslot = tid & 7;    // 0..7

    f32x4 acc[4][4] = {};

    for (int k0 = 0; k0 < K; k0 += 64) {
        #pragma unroll
        for (int rr = 0; rr < 128; rr += 32) {
            int r = rr + srow;
            int sw = (sslot ^ (r & 7)) * 8;
            int gr = rowBase + r; if (gr > M - 1) gr = M - 1;
            uint4 av = *(const uint4*)(A + (size_t)gr * K + k0 + sslot * 8);
            *(uint4*)&lds[r * 64 + sw] = av;
            int n = colBase + r;
            uint4 bv = *(const uint4*)(BT + (size_t)n * K + k0 + sslot * 8);
            *(uint4*)&lds[8192 + r * 64 + sw] = bv;
        }
        __syncthreads();
        #pragma unroll
        for (int kk = 0; kk < 2; ++kk) {
            int kslot = kk * 4 + lkg;
            int ssw = (kslot ^ (lrow & 7)) * 8;
            bf16x8 af[4], bfr[4];
            #pragma unroll
            for (int mi = 0; mi < 4; ++mi)
                af[mi] = *(const bf16x8*)&lds[(wm * 64 + mi * 16 + lrow) * 64 + ssw];
            #pragma unroll
            for (int ni = 0; ni < 4; ++ni)
                bfr[ni] = *(const bf16x8*)&lds[8192 + (wn * 64 + ni * 16 + lrow) * 64 + ssw];
            #pragma unroll
            for (int mi = 0; mi < 4; ++mi)
                #pragma unroll
                for (int ni = 0; ni < 4; ++ni)
                    acc[mi][ni] = __builtin_amdgcn_mfma_f32_16x16x32_bf16(
                        af[mi], bfr[ni], acc[mi][ni], 0, 0, 0);
        }
        __syncthreads();
    }

    #pragma unroll
    for (int ni = 0; ni < 4; ++ni) {
        int col = colBase + wn * 64 + ni * 16 + lrow;
        float bv = bias[col];
        #pragma unroll
        for (int mi = 0; mi < 4; ++mi) {
            int r0 = rowBase + wm * 64 + mi * 16 + lkg * 4;
            #pragma unroll
            for (int j = 0; j < 4; ++j) {
                int r = r0 + j;
                if (r < M) {
                    float v = acc[mi][ni][j] + bv;
                    if (OUTMODE == 0) {
                        ((float*)Cout)[(size_t)r * N + col] = v;
                    } else {
                        if (OUTMODE == 1) v = fmaxf(v, 0.f);
                        ((unsigned short*)Cout)[(size_t)r * N + col] = f2bf(v);
                    }
                }
            }
        }
    }
}

// ---------------------------------------------------------------- sampling
// Two-phase: phase1 (per-lane point math -> LDS descriptors), phase2 (gather+fma).
// oa row layout: [offsets(256) | attn logits(128)]; softmax fused here.
__global__ __launch_bounds__(256) void sample_kernel(
    const unsigned short* __restrict__ valb,  // (B, LEN, NH, DH) bf16
    const float* __restrict__ oa,             // (B*Lq, 384)
    const float* __restrict__ ref,            // (B*Lq, NL, 2)
    unsigned short* __restrict__ out)         // (B*Lq, NH, DH) bf16
{
    __shared__ int2 ent[8][64];

    const int tid = threadIdx.x;
    const int il = tid >> 5;          // item within block
    const int L  = tid & 31;
    const int item = blockIdx.x * 8 + il;     // (b*Lq)*NH + h ; grid exact
    const int h  = item & (NHH - 1);
    const int bq = item >> 3;
    const int b  = bq / LEN_TOT;

    const float* row = oa + (size_t)bq * 384;

    // ---- phase 1: lane L -> point p = L>>1, dy = L&1
    {
        int p = L >> 1, dy = L & 1;
        int lvl = p >> 2;
        int Wl = 160 >> lvl, Hl = 48 >> lvl;
        int ST = (lvl == 0) ? 0 : ((lvl == 1) ? 7680 : ((lvl == 2) ? 9600 : 10080));

        float logit = row[256 + h * 16 + p];
        float m = logit;
        #pragma unroll
        for (int mk = 1; mk <= 16; mk <<= 1) m = fmaxf(m, __shfl_xor(m, mk));
        float e = __expf(logit - m);
        float s = e;
        #pragma unroll
        for (int mk = 1; mk <= 16; mk <<= 1) s += __shfl_xor(s, mk);
        float a = 2.f * e / s;    // pairs double-count -> s = 2*sum

        float rx = ref[bq * 8 + lvl * 2 + 0];
        float ry = ref[bq * 8 + lvl * 2 + 1];
        float ox = row[h * 32 + p * 2 + 0];
        float oy = row[h * 32 + p * 2 + 1];
        float xx = fmaf(rx, (float)Wl, ox) - 0.5f;
        float yy = fmaf(ry, (float)Hl, oy) - 0.5f;
        float xf = floorf(xx), yf = floorf(yy);
        float fx = xx - xf, fy = yy - yf;
        int x0 = (int)xf, y0 = (int)yf;
        int yi = y0 + dy;
        float wy = dy ? fy : 1.f - fy;
        bool vy = (yi >= 0) && (yi < Hl);
        int yc = min(max(yi, 0), Hl - 1);
        int base = (b * LEN_TOT + ST) * 256 + h * 32;
        #pragma unroll
        for (int dx = 0; dx < 2; ++dx) {
            int xi = x0 + dx;
            float wx = dx ? fx : 1.f - fx;
            bool valid = vy && (xi >= 0) && (xi < Wl);
            int xc = min(max(xi, 0), Wl - 1);
            float w = valid ? a * wx * wy : 0.f;
            ent[il][p * 4 + dy * 2 + dx] =
                make_int2(base + (yc * Wl + xc) * 256, __float_as_int(w));
        }
    }
    __syncthreads();

    // ---- phase 2: lane = channel, 64 gathers
    float acc = 0.f;
    #pragma unroll 16
    for (int e2 = 0; e2 < 64; ++e2) {
        int2 d = ent[il][e2];
        unsigned short uv = valb[(size_t)d.x + L];
        float v = __uint_as_float((unsigned int)uv << 16);
        acc = fmaf(__int_as_float(d.y), v, acc);
    }
    out[(size_t)item * DHH + L] = f2bf(acc);
}

// ---------------------------------------------------------------- residual + LN (+ bf16 copy)
__global__ __launch_bounds__(256) void resln_kernel(
    float* __restrict__ x, const float* __restrict__ r,
    const float* __restrict__ g, const float* __restrict__ bta,
    unsigned short* __restrict__ xb)
{
    int row = blockIdx.x * 4 + (threadIdx.x >> 6);
    int lane = threadIdx.x & 63;
    if (row >= ROWS) return;
    float4 v  = *(const float4*)(x + (size_t)row * DD + lane * 4);
    float4 rr = *(const float4*)(r + (size_t)row * DD + lane * 4);
    v.x += rr.x; v.y += rr.y; v.z += rr.z; v.w += rr.w;
    float s  = v.x + v.y + v.z + v.w;
    float s2 = v.x * v.x + v.y * v.y + v.z * v.z + v.w * v.w;
    #pragma unroll
    for (int o = 1; o < 64; o <<= 1) {
        s  += __shfl_xor(s, o);
        s2 += __shfl_xor(s2, o);
    }
    float mean = s * (1.f / DD);
    float var  = s2 * (1.f / DD) - mean * mean;
    float inv  = rsqrtf(var + 1e-5f);
    float4 gg = *(const float4*)(g + lane * 4);
    float4 bb = *(const float4*)(bta + lane * 4);
    float4 o;
    o.x = (v.x - mean) * inv * gg.x + bb.x;
    o.y = (v.y - mean) * inv * gg.y + bb.y;
    o.z = (v.z - mean) * inv * gg.z + bb.z;
    o.w = (v.w - mean) * inv * gg.w + bb.w;
    *(float4*)(x + (size_t)row * DD + lane * 4) = o;
    uint2 ob;
    ob.x = pack2(o.x, o.y);
    ob.y = pack2(o.z, o.w);
    ((uint2*)(xb + (size_t)row * DD))[lane] = ob;
}

// ---------------------------------------------------------------- launch
extern "C" void kernel_launch(void* const* d_in, const int* in_sizes, int n_in,
                              void* d_out, int out_size, void* d_ws, size_t ws_size,
                              hipStream_t stream)
{
    const float* src    = (const float*)d_in[0];
    const float* pos    = (const float*)d_in[1];
    const float* vr     = (const float*)d_in[2];
    const float* W_off  = (const float*)d_in[3];
    const float* b_off  = (const float*)d_in[4];
    const float* W_attn = (const float*)d_in[5];
    const float* b_attn = (const float*)d_in[6];
    const float* W_val  = (const float*)d_in[7];
    const float* b_val  = (const float*)d_in[8];
    const float* W_out  = (const float*)d_in[9];
    const float* b_out  = (const float*)d_in[10];
    const float* ln1_g  = (const float*)d_in[11];
    const float* ln1_b  = (const float*)d_in[12];
    const float* W_ff1  = (const float*)d_in[13];
    const float* b_ff1  = (const float*)d_in[14];
    const float* W_ff2  = (const float*)d_in[15];
    const float* b_ff2  = (const float*)d_in[16];
    const float* ln2_g  = (const float*)d_in[17];
    const float* ln2_b  = (const float*)d_in[18];

    float* x = (float*)d_out;
    float* ws = (float*)d_ws;
    size_t o = 0;
    float* oa      = ws + o; o += (size_t)ROWS * 384;   // [off(256)|attn logits(128)]
    float* tmp     = ws + o; o += (size_t)ROWS * 256;
    float* ref     = ws + o; o += (size_t)ROWS * 8;
    float* bias_oa = ws + o; o += 3 * 384;

    unsigned short* ub = (unsigned short*)(ws + o);
    size_t uo = 0;
    unsigned short* q_bf    = ub + uo; uo += (size_t)ROWS * 256;
    unsigned short* x_bf    = ub + uo; uo += (size_t)ROWS * 256;
    unsigned short* samp_bf = ub + uo; uo += (size_t)ROWS * 256;
    unsigned short* val_bf  = ub + uo; uo += (size_t)ROWS * 256;
    unsigned short* h_bf    = ub + uo; uo += (size_t)ROWS * DFF_;
    unsigned short* WT_oa   = ub + uo; uo += (size_t)3 * 384 * 256;
    unsigned short* WT_val  = ub + uo; uo += (size_t)3 * 256 * 256;
    unsigned short* WT_out  = ub + uo; uo += (size_t)3 * 256 * 256;
    unsigned short* WT_ff1  = ub + uo; uo += (size_t)3 * 256 * 1024;
    unsigned short* WT_ff2  = ub + uo; uo += (size_t)3 * 1024 * 256;

    const int n8 = ROWS * DD / 8;

    convert_src_kernel<<<(n8 + 255) / 256, 256, 0, stream>>>(src, x, x_bf, n8);
    ref_points_kernel<<<(ROWS + 255) / 256, 256, 0, stream>>>(vr, ref);

    dim3 wtb(32, 8);
    wt_kernel<<<dim3(8,  8, 3), wtb, 0, stream>>>(W_off,  WT_oa,  256, 256,  384 * 256, 0);
    wt_kernel<<<dim3(8,  4, 3), wtb, 0, stream>>>(W_attn, WT_oa,  256, 128,  384 * 256, 256);
    wt_kernel<<<dim3(8,  8, 3), wtb, 0, stream>>>(W_val,  WT_val, 256, 256,  256 * 256, 0);
    wt_kernel<<<dim3(8,  8, 3), wtb, 0, stream>>>(W_out,  WT_out, 256, 256,  256 * 256, 0);
    wt_kernel<<<dim3(8, 32, 3), wtb, 0, stream>>>(W_ff1,  WT_ff1, 256, 1024, 256 * 1024, 0);
    wt_kernel<<<dim3(32, 8, 3), wtb, 0, stream>>>(W_ff2,  WT_ff2, 1024, 256, 1024 * 256, 0);
    bias_oa_kernel<<<(3 * 384 + 255) / 256, 256, 0, stream>>>(b_off, b_attn, bias_oa);

    dim3 g384(160, 3), g256(160, 2), g1024(160, 8);

    for (int l = 0; l < 3; ++l) {
        addq_kernel<<<(n8 + 255) / 256, 256, 0, stream>>>(x, pos, q_bf, n8);
        // [offs | attn logits] = q @ [W_off|W_attn] + bias
        gemm_bf16<0><<<g384, 256, 0, stream>>>(
            q_bf, WT_oa + (size_t)l * 384 * 256, bias_oa + (size_t)l * 384, oa,
            ROWS, 384, 256);
        // val (bf16 out)
        gemm_bf16<2><<<g256, 256, 0, stream>>>(
            x_bf, WT_val + (size_t)l * 65536, b_val + (size_t)l * 256, val_bf,
            ROWS, 256, 256);
        // deformable sampling (softmax fused)
        sample_kernel<<<ROWS * NHH / 8, 256, 0, stream>>>(
            val_bf, oa, ref, samp_bf);
        // att_out = samp @ W_out + b_out
        gemm_bf16<0><<<g256, 256, 0, stream>>>(
            samp_bf, WT_out + (size_t)l * 65536, b_out + (size_t)l * 256, tmp,
            ROWS, 256, 256);
        resln_kernel<<<(ROWS + 3) / 4, 256, 0, stream>>>(
            x, tmp, ln1_g + (size_t)l * 256, ln1_b + (size_t)l * 256, x_bf);
        gemm_bf16<1><<<g1024, 256, 0, stream>>>(
            x_bf, WT_ff1 + (size_t)l * 262144, b_ff1 + (size_t)l * 1024, h_bf,
            ROWS, 1024, 256);
        gemm_bf16<0><<<g256, 256, 0, stream>>>(
            h_bf, WT_ff2 + (size_t)l * 262144, b_ff2 + (size_t)l * 256, tmp,
            ROWS, 256, 1024);
        resln_kernel<<<(ROWS + 3) / 4, 256, 0, stream>>>(
            x, tmp, ln2_g + (size_t)l * 256, ln2_b + (size_t)l * 256, x_bf);
    }
}

// Round 6
// 694.679 us; speedup vs baseline: 2.7832x; 1.0520x over previous
//
#include <hip/hip_runtime.h>

typedef short bf16x8 __attribute__((ext_vector_type(8)));
typedef float f32x4  __attribute__((ext_vector_type(4)));

#define LEN_TOT 10200
#define BB 2
#define DD 256
#define NHH 8
#define NLL 4
#define NPP 4
#define DHH 32
#define DFF_ 1024
#define ROWS (BB * LEN_TOT)   // 20400

__device__ inline unsigned short f2bf(float f) {
    unsigned int u = __float_as_uint(f);
    u += 0x7fffu + ((u >> 16) & 1u);     // RNE
    return (unsigned short)(u >> 16);
}
__device__ inline unsigned int pack2(float a, float b) {
    return (unsigned int)f2bf(a) | ((unsigned int)f2bf(b) << 16);
}
__device__ inline float bflo(unsigned int u) { return __uint_as_float(u << 16); }
__device__ inline float bfhi(unsigned int u) { return __uint_as_float(u & 0xffff0000u); }
__device__ inline float bfs(unsigned short u) { return __uint_as_float((unsigned int)u << 16); }

// ---------------------------------------------------------------- ref points
__global__ __launch_bounds__(256) void ref_points_kernel(
    const float* __restrict__ vr, float* __restrict__ ref)
{
    int i = blockIdx.x * blockDim.x + threadIdx.x;
    if (i >= BB * LEN_TOT) return;
    int b = i / LEN_TOT, pos = i % LEN_TOT;
    int lvl, st, Hl, Wl;
    if (pos < 7680)      { lvl = 0; st = 0;     Hl = 48; Wl = 160; }
    else if (pos < 9600) { lvl = 1; st = 7680;  Hl = 24; Wl = 80;  }
    else if (pos < 10080){ lvl = 2; st = 9600;  Hl = 12; Wl = 40;  }
    else                 { lvl = 3; st = 10080; Hl = 6;  Wl = 20;  }
    int local = pos - st;
    int row = local / Wl, col = local % Wl;
    float rx = (col + 0.5f) / (vr[(b * NLL + lvl) * 2 + 0] * (float)Wl);
    float ry = (row + 0.5f) / (vr[(b * NLL + lvl) * 2 + 1] * (float)Hl);
    #pragma unroll
    for (int ol = 0; ol < NLL; ++ol) {
        ref[((size_t)i * NLL + ol) * 2 + 0] = rx * vr[(b * NLL + ol) * 2 + 0];
        ref[((size_t)i * NLL + ol) * 2 + 1] = ry * vr[(b * NLL + ol) * 2 + 1];
    }
}

// ---------------------------------------------------------------- src -> x fp32 + x bf16 + q bf16
__global__ __launch_bounds__(256) void convert_src_kernel(
    const float* __restrict__ src, const float* __restrict__ pos,
    float* __restrict__ x, unsigned short* __restrict__ xb,
    unsigned short* __restrict__ qb, int n8)
{
    int i = blockIdx.x * blockDim.x + threadIdx.x;
    if (i >= n8) return;
    float4 a = ((const float4*)src)[2 * i];
    float4 b = ((const float4*)src)[2 * i + 1];
    ((float4*)x)[2 * i]     = a;
    ((float4*)x)[2 * i + 1] = b;
    uint4 o;
    o.x = pack2(a.x, a.y); o.y = pack2(a.z, a.w);
    o.z = pack2(b.x, b.y); o.w = pack2(b.z, b.w);
    ((uint4*)xb)[i] = o;
    float4 p0 = ((const float4*)pos)[2 * i];
    float4 p1 = ((const float4*)pos)[2 * i + 1];
    uint4 oq;
    oq.x = pack2(a.x + p0.x, a.y + p0.y);
    oq.y = pack2(a.z + p0.z, a.w + p0.w);
    oq.z = pack2(b.x + p1.x, b.y + p1.y);
    oq.w = pack2(b.z + p1.z, b.w + p1.w);
    ((uint4*)qb)[i] = oq;
}

// ---------------------------------------------------------------- weight transpose
// fp32 W[K][N] (layer z) -> bf16 WT rows: WT[z*ldOut + (rowOff+n)*K + k]
__global__ __launch_bounds__(256) void wt_kernel(
    const float* __restrict__ W, unsigned short* __restrict__ WT,
    int K, int N, int ldOut, int rowOff)
{
    __shared__ float t[32][33];
    const float* Wl = W + (size_t)blockIdx.z * K * N;
    unsigned short* WTl = WT + (size_t)blockIdx.z * ldOut;
    int kb = blockIdx.x * 32, nb = blockIdx.y * 32;
    int tx = threadIdx.x, ty = threadIdx.y;   // 32 x 8
    #pragma unroll
    for (int i = 0; i < 4; ++i)
        t[ty + i * 8][tx] = Wl[(size_t)(kb + ty + i * 8) * N + nb + tx];
    __syncthreads();
    #pragma unroll
    for (int i = 0; i < 4; ++i)
        WTl[(size_t)(rowOff + nb + ty + i * 8) * K + kb + tx] = f2bf(t[tx][ty + i * 8]);
}

// ---------------------------------------------------------------- bias concat [b_off(256) | b_attn(128)] per layer
__global__ __launch_bounds__(256) void bias_oa_kernel(
    const float* __restrict__ b_off, const float* __restrict__ b_attn,
    float* __restrict__ out)
{
    int i = blockIdx.x * blockDim.x + threadIdx.x;
    if (i >= 3 * 384) return;
    int l = i / 384, j = i % 384;
    out[i] = (j < 256) ? b_off[l * 256 + j] : b_attn[l * 128 + (j - 256)];
}

// ---------------------------------------------------------------- bf16 MFMA GEMM
// C[M,N] = A[M,K](bf16) @ (BT[N,K](bf16))^T + bias.
// OUTMODE 0: fp32 out; 1: relu->bf16; 2: bf16.
// 128x128 tile, BK=64, 4 waves each 64x64.
// Staging: global_load_lds w=16, LINEAR LDS dest, source k-slot pre-XOR'd with (row&7)
// (T21: same involution applied on the read side below).
template<int OUTMODE>
__global__ __launch_bounds__(256) void gemm_bf16(
    const unsigned short* __restrict__ A,
    const unsigned short* __restrict__ BT,
    const float* __restrict__ bias,
    void* __restrict__ Cout,
    int M, int N, int K)
{
    __shared__ short lds[2 * 128 * 64];
    const int tid = threadIdx.x;
    const int l   = tid & 63;
    const int wid = tid >> 6;
    const int wm  = wid >> 1, wn = wid & 1;
    const int lrow = l & 15, lkg = l >> 4;
    const int rowBase = blockIdx.x * 128;
    const int colBase = blockIdx.y * 128;

    f32x4 acc[4][4] = {};

    for (int k0 = 0; k0 < K; k0 += 64) {
        #pragma unroll
        for (int it = 0; it < 4; ++it) {
            int sidx = tid + 256 * it;        // 0..1023 : row r = sidx>>3, slot s = sidx&7
            int r = sidx >> 3;
            int ss = ((sidx & 7) ^ (r & 7)) * 8;   // pre-swizzled source k-offset
            int gr = rowBase + r; if (gr > M - 1) gr = M - 1;
            __builtin_amdgcn_global_load_lds(
                (const __attribute__((address_space(1))) unsigned int*)
                    (A + (size_t)gr * K + k0 + ss),
                (__attribute__((address_space(3))) unsigned int*)&lds[sidx * 8],
                16, 0, 0);
            __builtin_amdgcn_global_load_lds(
                (const __attribute__((address_space(1))) unsigned int*)
                    (BT + (size_t)(colBase + r) * K + k0 + ss),
                (__attribute__((address_space(3))) unsigned int*)&lds[8192 + sidx * 8],
                16, 0, 0);
        }
        __syncthreads();
        #pragma unroll
        for (int kk = 0; kk < 2; ++kk) {
            int kslot = kk * 4 + lkg;
            int ssw = (kslot ^ (lrow & 7)) * 8;
            bf16x8 af[4], bfr[4];
            #pragma unroll
            for (int mi = 0; mi < 4; ++mi)
                af[mi] = *(const bf16x8*)&lds[(wm * 64 + mi * 16 + lrow) * 64 + ssw];
            #pragma unroll
            for (int ni = 0; ni < 4; ++ni)
                bfr[ni] = *(const bf16x8*)&lds[8192 + (wn * 64 + ni * 16 + lrow) * 64 + ssw];
            #pragma unroll
            for (int mi = 0; mi < 4; ++mi)
                #pragma unroll
                for (int ni = 0; ni < 4; ++ni)
                    acc[mi][ni] = __builtin_amdgcn_mfma_f32_16x16x32_bf16(
                        af[mi], bfr[ni], acc[mi][ni], 0, 0, 0);
        }
        __syncthreads();
    }

    #pragma unroll
    for (int ni = 0; ni < 4; ++ni) {
        int col = colBase + wn * 64 + ni * 16 + lrow;
        float bv = bias[col];
        #pragma unroll
        for (int mi = 0; mi < 4; ++mi) {
            int r0 = rowBase + wm * 64 + mi * 16 + lkg * 4;
            #pragma unroll
            for (int j = 0; j < 4; ++j) {
                int r = r0 + j;
                if (r < M) {
                    float v = acc[mi][ni][j] + bv;
                    if (OUTMODE == 0) {
                        ((float*)Cout)[(size_t)r * N + col] = v;
                    } else {
                        if (OUTMODE == 1) v = fmaxf(v, 0.f);
                        ((unsigned short*)Cout)[(size_t)r * N + col] = f2bf(v);
                    }
                }
            }
        }
    }
}

// ---------------------------------------------------------------- sampling
// Phase 1: lane L -> (point p=L>>1, dy=L&1): softmax + bilinear -> 64 (addr,weight) in LDS.
// Phase 2: lane L -> (chan-octet oct=L&3, stripe sub=L>>2): 8 x dwordx4 gathers,
//          shfl-reduce over sub, lanes sub==0 store 16B.
__global__ __launch_bounds__(256) void sample_kernel(
    const unsigned short* __restrict__ valb,  // (B, LEN, NH, DH) bf16
    const unsigned short* __restrict__ oa,    // (B*Lq, 384) bf16 [off(256)|logits(128)]
    const float* __restrict__ ref,            // (B*Lq, NL, 2)
    unsigned short* __restrict__ out)         // (B*Lq, NH, DH) bf16
{
    __shared__ int2 ent[8][64];

    const int tid = threadIdx.x;
    const int il = tid >> 5;
    const int L  = tid & 31;
    const int item = blockIdx.x * 8 + il;     // (b*Lq)*NH + h ; grid exact
    const int h  = item & (NHH - 1);
    const int bq = item >> 3;
    const int b  = bq / LEN_TOT;

    const unsigned short* row = oa + (size_t)bq * 384;

    // ---- phase 1
    {
        int p = L >> 1, dy = L & 1;
        int lvl = p >> 2;
        int Wl = 160 >> lvl, Hl = 48 >> lvl;
        int ST = (lvl == 0) ? 0 : ((lvl == 1) ? 7680 : ((lvl == 2) ? 9600 : 10080));

        float logit = bfs(row[256 + h * 16 + p]);
        float m = logit;
        #pragma unroll
        for (int mk = 1; mk <= 16; mk <<= 1) m = fmaxf(m, __shfl_xor(m, mk));
        float e = __expf(logit - m);
        float s = e;
        #pragma unroll
        for (int mk = 1; mk <= 16; mk <<= 1) s += __shfl_xor(s, mk);
        float a = 2.f * e / s;    // pairs double-count -> s = 2*sum

        float rx = ref[bq * 8 + lvl * 2 + 0];
        float ry = ref[bq * 8 + lvl * 2 + 1];
        float ox = bfs(row[h * 32 + p * 2 + 0]);
        float oy = bfs(row[h * 32 + p * 2 + 1]);
        float xx = fmaf(rx, (float)Wl, ox) - 0.5f;
        float yy = fmaf(ry, (float)Hl, oy) - 0.5f;
        float xf = floorf(xx), yf = floorf(yy);
        float fx = xx - xf, fy = yy - yf;
        int x0 = (int)xf, y0 = (int)yf;
        int yi = y0 + dy;
        float wy = dy ? fy : 1.f - fy;
        bool vy = (yi >= 0) && (yi < Hl);
        int yc = min(max(yi, 0), Hl - 1);
        int base = (b * LEN_TOT + ST) * 256 + h * 32;
        #pragma unroll
        for (int dx = 0; dx < 2; ++dx) {
            int xi = x0 + dx;
            float wx = dx ? fx : 1.f - fx;
            bool valid = vy && (xi >= 0) && (xi < Wl);
            int xc = min(max(xi, 0), Wl - 1);
            float w = valid ? a * wx * wy : 0.f;
            ent[il][p * 4 + dy * 2 + dx] =
                make_int2(base + (yc * Wl + xc) * 256, __float_as_int(w));
        }
    }
    __syncthreads();

    // ---- phase 2
    const int oct = L & 3;        // channels oct*8 .. oct*8+7
    const int sub = L >> 2;       // entry stripe 0..7
    float a0 = 0.f, a1 = 0.f, a2 = 0.f, a3 = 0.f;
    float a4 = 0.f, a5 = 0.f, a6 = 0.f, a7 = 0.f;
    #pragma unroll
    for (int i = 0; i < 8; ++i) {
        int2 d = ent[il][sub + 8 * i];
        float w = __int_as_float(d.y);
        uint4 v = *(const uint4*)(valb + (size_t)(unsigned)d.x + oct * 8);
        a0 = fmaf(w, bflo(v.x), a0); a1 = fmaf(w, bfhi(v.x), a1);
        a2 = fmaf(w, bflo(v.y), a2); a3 = fmaf(w, bfhi(v.y), a3);
        a4 = fmaf(w, bflo(v.z), a4); a5 = fmaf(w, bfhi(v.z), a5);
        a6 = fmaf(w, bflo(v.w), a6); a7 = fmaf(w, bfhi(v.w), a7);
    }
    #pragma unroll
    for (int mk = 4; mk <= 16; mk <<= 1) {
        a0 += __shfl_xor(a0, mk); a1 += __shfl_xor(a1, mk);
        a2 += __shfl_xor(a2, mk); a3 += __shfl_xor(a3, mk);
        a4 += __shfl_xor(a4, mk); a5 += __shfl_xor(a5, mk);
        a6 += __shfl_xor(a6, mk); a7 += __shfl_xor(a7, mk);
    }
    if (sub == 0) {
        uint4 o;
        o.x = pack2(a0, a1); o.y = pack2(a2, a3);
        o.z = pack2(a4, a5); o.w = pack2(a6, a7);
        *(uint4*)(out + (size_t)item * DHH + oct * 8) = o;
    }
}

// ---------------------------------------------------------------- residual + LN (+ bf16 copy, + optional q=bf16(out+pos))
__global__ __launch_bounds__(256) void resln_kernel(
    float* __restrict__ x, const float* __restrict__ r,
    const float* __restrict__ g, const float* __restrict__ bta,
    unsigned short* __restrict__ xb,
    const float* __restrict__ pos, unsigned short* __restrict__ qb)
{
    int row = blockIdx.x * 4 + (threadIdx.x >> 6);
    int lane = threadIdx.x & 63;
    if (row >= ROWS) return;
    float4 v  = *(const float4*)(x + (size_t)row * DD + lane * 4);
    float4 rr = *(const float4*)(r + (size_t)row * DD + lane * 4);
    v.x += rr.x; v.y += rr.y; v.z += rr.z; v.w += rr.w;
    float s  = v.x + v.y + v.z + v.w;
    float s2 = v.x * v.x + v.y * v.y + v.z * v.z + v.w * v.w;
    #pragma unroll
    for (int o = 1; o < 64; o <<= 1) {
        s  += __shfl_xor(s, o);
        s2 += __shfl_xor(s2, o);
    }
    float mean = s * (1.f / DD);
    float var  = s2 * (1.f / DD) - mean * mean;
    float inv  = rsqrtf(var + 1e-5f);
    float4 gg = *(const float4*)(g + lane * 4);
    float4 bb = *(const float4*)(bta + lane * 4);
    float4 o;
    o.x = (v.x - mean) * inv * gg.x + bb.x;
    o.y = (v.y - mean) * inv * gg.y + bb.y;
    o.z = (v.z - mean) * inv * gg.z + bb.z;
    o.w = (v.w - mean) * inv * gg.w + bb.w;
    *(float4*)(x + (size_t)row * DD + lane * 4) = o;
    uint2 ob;
    ob.x = pack2(o.x, o.y);
    ob.y = pack2(o.z, o.w);
    ((uint2*)(xb + (size_t)row * DD))[lane] = ob;
    if (qb) {
        float4 pv = *(const float4*)(pos + (size_t)row * DD + lane * 4);
        uint2 oq;
        oq.x = pack2(o.x + pv.x, o.y + pv.y);
        oq.y = pack2(o.z + pv.z, o.w + pv.w);
        ((uint2*)(qb + (size_t)row * DD))[lane] = oq;
    }
}

// ---------------------------------------------------------------- launch
extern "C" void kernel_launch(void* const* d_in, const int* in_sizes, int n_in,
                              void* d_out, int out_size, void* d_ws, size_t ws_size,
                              hipStream_t stream)
{
    const float* src    = (const float*)d_in[0];
    const float* pos    = (const float*)d_in[1];
    const float* vr     = (const float*)d_in[2];
    const float* W_off  = (const float*)d_in[3];
    const float* b_off  = (const float*)d_in[4];
    const float* W_attn = (const float*)d_in[5];
    const float* b_attn = (const float*)d_in[6];
    const float* W_val  = (const float*)d_in[7];
    const float* b_val  = (const float*)d_in[8];
    const float* W_out  = (const float*)d_in[9];
    const float* b_out  = (const float*)d_in[10];
    const float* ln1_g  = (const float*)d_in[11];
    const float* ln1_b  = (const float*)d_in[12];
    const float* W_ff1  = (const float*)d_in[13];
    const float* b_ff1  = (const float*)d_in[14];
    const float* W_ff2  = (const float*)d_in[15];
    const float* b_ff2  = (const float*)d_in[16];
    const float* ln2_g  = (const float*)d_in[17];
    const float* ln2_b  = (const float*)d_in[18];

    float* x = (float*)d_out;
    float* ws = (float*)d_ws;
    size_t o = 0;
    float* tmp     = ws + o; o += (size_t)ROWS * 256;
    float* ref     = ws + o; o += (size_t)ROWS * 8;
    float* bias_oa = ws + o; o += 3 * 384;

    unsigned short* ub = (unsigned short*)(ws + o);
    size_t uo = 0;
    unsigned short* oa      = ub + uo; uo += (size_t)ROWS * 384;
    unsigned short* q_bf    = ub + uo; uo += (size_t)ROWS * 256;
    unsigned short* x_bf    = ub + uo; uo += (size_t)ROWS * 256;
    unsigned short* samp_bf = ub + uo; uo += (size_t)ROWS * 256;
    unsigned short* val_bf  = ub + uo; uo += (size_t)ROWS * 256;
    unsigned short* h_bf    = ub + uo; uo += (size_t)ROWS * DFF_;
    unsigned short* WT_oa   = ub + uo; uo += (size_t)3 * 384 * 256;
    unsigned short* WT_val  = ub + uo; uo += (size_t)3 * 256 * 256;
    unsigned short* WT_out  = ub + uo; uo += (size_t)3 * 256 * 256;
    unsigned short* WT_ff1  = ub + uo; uo += (size_t)3 * 256 * 1024;
    unsigned short* WT_ff2  = ub + uo; uo += (size_t)3 * 1024 * 256;

    const int n8 = ROWS * DD / 8;

    convert_src_kernel<<<(n8 + 255) / 256, 256, 0, stream>>>(src, pos, x, x_bf, q_bf, n8);
    ref_points_kernel<<<(ROWS + 255) / 256, 256, 0, stream>>>(vr, ref);

    dim3 wtb(32, 8);
    wt_kernel<<<dim3(8,  8, 3), wtb, 0, stream>>>(W_off,  WT_oa,  256, 256,  384 * 256, 0);
    wt_kernel<<<dim3(8,  4, 3), wtb, 0, stream>>>(W_attn, WT_oa,  256, 128,  384 * 256, 256);
    wt_kernel<<<dim3(8,  8, 3), wtb, 0, stream>>>(W_val,  WT_val, 256, 256,  256 * 256, 0);
    wt_kernel<<<dim3(8,  8, 3), wtb, 0, stream>>>(W_out,  WT_out, 256, 256,  256 * 256, 0);
    wt_kernel<<<dim3(8, 32, 3), wtb, 0, stream>>>(W_ff1,  WT_ff1, 256, 1024, 256 * 1024, 0);
    wt_kernel<<<dim3(32, 8, 3), wtb, 0, stream>>>(W_ff2,  WT_ff2, 1024, 256, 1024 * 256, 0);
    bias_oa_kernel<<<(3 * 384 + 255) / 256, 256, 0, stream>>>(b_off, b_attn, bias_oa);

    dim3 g384(160, 3), g256(160, 2), g1024(160, 8);

    for (int l = 0; l < 3; ++l) {
        // [offs | attn logits] = q @ [W_off|W_attn] + bias  (bf16 out)
        gemm_bf16<2><<<g384, 256, 0, stream>>>(
            q_bf, WT_oa + (size_t)l * 384 * 256, bias_oa + (size_t)l * 384, oa,
            ROWS, 384, 256);
        // val (bf16 out)
        gemm_bf16<2><<<g256, 256, 0, stream>>>(
            x_bf, WT_val + (size_t)l * 65536, b_val + (size_t)l * 256, val_bf,
            ROWS, 256, 256);
        // deformable sampling (softmax fused)
        sample_kernel<<<ROWS * NHH / 8, 256, 0, stream>>>(
            val_bf, oa, ref, samp_bf);
        // att_out = samp @ W_out + b_out
        gemm_bf16<0><<<g256, 256, 0, stream>>>(
            samp_bf, WT_out + (size_t)l * 65536, b_out + (size_t)l * 256, tmp,
            ROWS, 256, 256);
        resln_kernel<<<(ROWS + 3) / 4, 256, 0, stream>>>(
            x, tmp, ln1_g + (size_t)l * 256, ln1_b + (size_t)l * 256, x_bf,
            nullptr, nullptr);
        gemm_bf16<1><<<g1024, 256, 0, stream>>>(
            x_bf, WT_ff1 + (size_t)l * 262144, b_ff1 + (size_t)l * 1024, h_bf,
            ROWS, 1024, 256);
        gemm_bf16<0><<<g256, 256, 0, stream>>>(
            h_bf, WT_ff2 + (size_t)l * 262144, b_ff2 + (size_t)l * 256, tmp,
            ROWS, 256, 1024);
        resln_kernel<<<(ROWS + 3) / 4, 256, 0, stream>>>(
            x, tmp, ln2_g + (size_t)l * 256, ln2_b + (size_t)l * 256, x_bf,
            (l < 2) ? pos : nullptr, (l < 2) ? q_bf : nullptr);
    }
}

// Round 15
// 634.823 us; speedup vs baseline: 3.0456x; 1.0943x over previous
//
#include <hip/hip_runtime.h>

typedef short bf16x8 __attribute__((ext_vector_type(8)));
typedef float f32x4  __attribute__((ext_vector_type(4)));

#define LEN_TOT 10200
#define BB 2
#define DD 256
#define NHH 8
#define NLL 4
#define NPP 4
#define DHH 32
#define DFF_ 1024
#define ROWS (BB * LEN_TOT)   // 20400

__device__ inline unsigned short f2bf(float f) {
    unsigned int u = __float_as_uint(f);
    u += 0x7fffu + ((u >> 16) & 1u);     // RNE
    return (unsigned short)(u >> 16);
}
__device__ inline unsigned int pack2(float a, float b) {
    return (unsigned int)f2bf(a) | ((unsigned int)f2bf(b) << 16);
}
__device__ inline float bflo(unsigned int u) { return __uint_as_float(u << 16); }
__device__ inline float bfhi(unsigned int u) { return __uint_as_float(u & 0xffff0000u); }
__device__ inline float bfs(unsigned short u) { return __uint_as_float((unsigned int)u << 16); }

// ---------------------------------------------------------------- ref points
__global__ __launch_bounds__(256) void ref_points_kernel(
    const float* __restrict__ vr, float* __restrict__ ref)
{
    int i = blockIdx.x * blockDim.x + threadIdx.x;
    if (i >= BB * LEN_TOT) return;
    int b = i / LEN_TOT, pos = i % LEN_TOT;
    int lvl, st, Hl, Wl;
    if (pos < 7680)      { lvl = 0; st = 0;     Hl = 48; Wl = 160; }
    else if (pos < 9600) { lvl = 1; st = 7680;  Hl = 24; Wl = 80;  }
    else if (pos < 10080){ lvl = 2; st = 9600;  Hl = 12; Wl = 40;  }
    else                 { lvl = 3; st = 10080; Hl = 6;  Wl = 20;  }
    int local = pos - st;
    int row = local / Wl, col = local % Wl;
    float rx = (col + 0.5f) / (vr[(b * NLL + lvl) * 2 + 0] * (float)Wl);
    float ry = (row + 0.5f) / (vr[(b * NLL + lvl) * 2 + 1] * (float)Hl);
    #pragma unroll
    for (int ol = 0; ol < NLL; ++ol) {
        ref[((size_t)i * NLL + ol) * 2 + 0] = rx * vr[(b * NLL + ol) * 2 + 0];
        ref[((size_t)i * NLL + ol) * 2 + 1] = ry * vr[(b * NLL + ol) * 2 + 1];
    }
}

// ---------------------------------------------------------------- src -> x fp32 + x bf16 + q bf16
__global__ __launch_bounds__(256) void convert_src_kernel(
    const float* __restrict__ src, const float* __restrict__ pos,
    float* __restrict__ x, unsigned short* __restrict__ xb,
    unsigned short* __restrict__ qb, int n8)
{
    int i = blockIdx.x * blockDim.x + threadIdx.x;
    if (i >= n8) return;
    float4 a = ((const float4*)src)[2 * i];
    float4 b = ((const float4*)src)[2 * i + 1];
    ((float4*)x)[2 * i]     = a;
    ((float4*)x)[2 * i + 1] = b;
    uint4 o;
    o.x = pack2(a.x, a.y); o.y = pack2(a.z, a.w);
    o.z = pack2(b.x, b.y); o.w = pack2(b.z, b.w);
    ((uint4*)xb)[i] = o;
    float4 p0 = ((const float4*)pos)[2 * i];
    float4 p1 = ((const float4*)pos)[2 * i + 1];
    uint4 oq;
    oq.x = pack2(a.x + p0.x, a.y + p0.y);
    oq.y = pack2(a.z + p0.z, a.w + p0.w);
    oq.z = pack2(b.x + p1.x, b.y + p1.y);
    oq.w = pack2(b.z + p1.z, b.w + p1.w);
    ((uint4*)qb)[i] = oq;
}

// ---------------------------------------------------------------- weight transpose
// fp32 W[K][N] (layer z) -> bf16 WT rows: WT[z*ldOut + (rowOff+n)*K + k]
__global__ __launch_bounds__(256) void wt_kernel(
    const float* __restrict__ W, unsigned short* __restrict__ WT,
    int K, int N, int ldOut, int rowOff)
{
    __shared__ float t[32][33];
    const float* Wl = W + (size_t)blockIdx.z * K * N;
    unsigned short* WTl = WT + (size_t)blockIdx.z * ldOut;
    int kb = blockIdx.x * 32, nb = blockIdx.y * 32;
    int tx = threadIdx.x, ty = threadIdx.y;   // 32 x 8
    #pragma unroll
    for (int i = 0; i < 4; ++i)
        t[ty + i * 8][tx] = Wl[(size_t)(kb + ty + i * 8) * N + nb + tx];
    __syncthreads();
    #pragma unroll
    for (int i = 0; i < 4; ++i)
        WTl[(size_t)(rowOff + nb + ty + i * 8) * K + kb + tx] = f2bf(t[tx][ty + i * 8]);
}

// ---------------------------------------------------------------- bias concat [b_off(256) | b_attn(128)] per layer
__global__ __launch_bounds__(256) void bias_oa_kernel(
    const float* __restrict__ b_off, const float* __restrict__ b_attn,
    float* __restrict__ out)
{
    int i = blockIdx.x * blockDim.x + threadIdx.x;
    if (i >= 3 * 384) return;
    int l = i / 384, j = i % 384;
    out[i] = (j < 256) ? b_off[l * 256 + j] : b_attn[l * 128 + (j - 256)];
}

// ---------------------------------------------------------------- bf16 MFMA GEMM
// C[M,N] = A[M,K](bf16) @ (BT[N,K](bf16))^T + bias.
// OUTMODE 0: fp32 out; 1: relu->bf16; 2: bf16.
// BM x BN tile, BK=64, 4 waves in 2x2, each wave (BM/2)x(BN/2).
// Staging: global_load_lds w=16, LINEAR LDS dest, source k-slot pre-XOR'd with (row&7)
// (T21: same involution applied on the read side below).
template<int BM, int BN, int OUTMODE>
__global__ __launch_bounds__(256) void gemm_bf16(
    const unsigned short* __restrict__ A,
    const unsigned short* __restrict__ BT,
    const float* __restrict__ bias,
    void* __restrict__ Cout,
    int M, int N, int K)
{
    constexpr int WM = BM / 2, WN = BN / 2;   // per-wave output
    constexpr int FM = WM / 16, FN = WN / 16; // fragment repeats
    __shared__ short lds[(BM + BN) * 64];
    const int tid = threadIdx.x;
    const int l   = tid & 63;
    const int wid = tid >> 6;
    const int wm  = wid >> 1, wn = wid & 1;
    const int lrow = l & 15, lkg = l >> 4;
    const int rowBase = blockIdx.x * BM;
    const int colBase = blockIdx.y * BN;

    f32x4 acc[FM][FN] = {};

    for (int k0 = 0; k0 < K; k0 += 64) {
        #pragma unroll
        for (int it = 0; it < BM / 32; ++it) {
            int sidx = tid + 256 * it;        // row r = sidx>>3, slot s = sidx&7
            int r = sidx >> 3;
            int ss = ((sidx & 7) ^ (r & 7)) * 8;   // pre-swizzled source k-offset
            int gr = rowBase + r; if (gr > M - 1) gr = M - 1;
            __builtin_amdgcn_global_load_lds(
                (const __attribute__((address_space(1))) unsigned int*)
                    (A + (size_t)gr * K + k0 + ss),
                (__attribute__((address_space(3))) unsigned int*)&lds[sidx * 8],
                16, 0, 0);
        }
        #pragma unroll
        for (int it = 0; it < BN / 32; ++it) {
            int sidx = tid + 256 * it;
            int r = sidx >> 3;
            int ss = ((sidx & 7) ^ (r & 7)) * 8;
            __builtin_amdgcn_global_load_lds(
                (const __attribute__((address_space(1))) unsigned int*)
                    (BT + (size_t)(colBase + r) * K + k0 + ss),
                (__attribute__((address_space(3))) unsigned int*)&lds[BM * 64 + sidx * 8],
                16, 0, 0);
        }
        __syncthreads();
        #pragma unroll
        for (int kk = 0; kk < 2; ++kk) {
            int kslot = kk * 4 + lkg;
            int ssw = (kslot ^ (lrow & 7)) * 8;
            bf16x8 af[FM], bfr[FN];
            #pragma unroll
            for (int mi = 0; mi < FM; ++mi)
                af[mi] = *(const bf16x8*)&lds[(wm * WM + mi * 16 + lrow) * 64 + ssw];
            #pragma unroll
            for (int ni = 0; ni < FN; ++ni)
                bfr[ni] = *(const bf16x8*)&lds[BM * 64 + (wn * WN + ni * 16 + lrow) * 64 + ssw];
            #pragma unroll
            for (int mi = 0; mi < FM; ++mi)
                #pragma unroll
                for (int ni = 0; ni < FN; ++ni)
                    acc[mi][ni] = __builtin_amdgcn_mfma_f32_16x16x32_bf16(
                        af[mi], bfr[ni], acc[mi][ni], 0, 0, 0);
        }
        __syncthreads();
    }

    #pragma unroll
    for (int ni = 0; ni < FN; ++ni) {
        int col = colBase + wn * WN + ni * 16 + lrow;
        float bv = bias[col];
        #pragma unroll
        for (int mi = 0; mi < FM; ++mi) {
            int r0 = rowBase + wm * WM + mi * 16 + lkg * 4;
            #pragma unroll
            for (int j = 0; j < 4; ++j) {
                int r = r0 + j;
                if (r < M) {
                    float v = acc[mi][ni][j] + bv;
                    if (OUTMODE == 0) {
                        ((float*)Cout)[(size_t)r * N + col] = v;
                    } else {
                        if (OUTMODE == 1) v = fmaxf(v, 0.f);
                        ((unsigned short*)Cout)[(size_t)r * N + col] = f2bf(v);
                    }
                }
            }
        }
    }
}

// ---------------------------------------------------------------- sampling
// Phase 1: lane L -> (point p=L>>1, dy=L&1): softmax + bilinear -> 64 (addr,weight) in LDS.
// Phase 2: lane L -> (chan-octet oct=L&3, stripe sub=L>>2): 8 x dwordx4 gathers,
//          shfl-reduce over sub, lanes sub==0 store 16B.
__global__ __launch_bounds__(256) void sample_kernel(
    const unsigned short* __restrict__ valb,  // (B, LEN, NH, DH) bf16
    const unsigned short* __restrict__ oa,    // (B*Lq, 384) bf16 [off(256)|logits(128)]
    const float* __restrict__ ref,            // (B*Lq, NL, 2)
    unsigned short* __restrict__ out)         // (B*Lq, NH, DH) bf16
{
    __shared__ int2 ent[8][64];

    const int tid = threadIdx.x;
    const int il = tid >> 5;
    const int L  = tid & 31;
    const int item = blockIdx.x * 8 + il;     // (b*Lq)*NH + h ; grid exact
    const int h  = item & (NHH - 1);
    const int bq = item >> 3;
    const int b  = bq / LEN_TOT;

    const unsigned short* row = oa + (size_t)bq * 384;

    // ---- phase 1
    {
        int p = L >> 1, dy = L & 1;
        int lvl = p >> 2;
        int Wl = 160 >> lvl, Hl = 48 >> lvl;
        int ST = (lvl == 0) ? 0 : ((lvl == 1) ? 7680 : ((lvl == 2) ? 9600 : 10080));

        float logit = bfs(row[256 + h * 16 + p]);
        float m = logit;
        #pragma unroll
        for (int mk = 1; mk <= 16; mk <<= 1) m = fmaxf(m, __shfl_xor(m, mk));
        float e = __expf(logit - m);
        float s = e;
        #pragma unroll
        for (int mk = 1; mk <= 16; mk <<= 1) s += __shfl_xor(s, mk);
        float a = 2.f * e / s;    // pairs double-count -> s = 2*sum

        float rx = ref[bq * 8 + lvl * 2 + 0];
        float ry = ref[bq * 8 + lvl * 2 + 1];
        float ox = bfs(row[h * 32 + p * 2 + 0]);
        float oy = bfs(row[h * 32 + p * 2 + 1]);
        float xx = fmaf(rx, (float)Wl, ox) - 0.5f;
        float yy = fmaf(ry, (float)Hl, oy) - 0.5f;
        float xf = floorf(xx), yf = floorf(yy);
        float fx = xx - xf, fy = yy - yf;
        int x0 = (int)xf, y0 = (int)yf;
        int yi = y0 + dy;
        float wy = dy ? fy : 1.f - fy;
        bool vy = (yi >= 0) && (yi < Hl);
        int yc = min(max(yi, 0), Hl - 1);
        int base = (b * LEN_TOT + ST) * 256 + h * 32;
        #pragma unroll
        for (int dx = 0; dx < 2; ++dx) {
            int xi = x0 + dx;
            float wx = dx ? fx : 1.f - fx;
            bool valid = vy && (xi >= 0) && (xi < Wl);
            int xc = min(max(xi, 0), Wl - 1);
            float w = valid ? a * wx * wy : 0.f;
            ent[il][p * 4 + dy * 2 + dx] =
                make_int2(base + (yc * Wl + xc) * 256, __float_as_int(w));
        }
    }
    __syncthreads();

    // ---- phase 2
    const int oct = L & 3;        // channels oct*8 .. oct*8+7
    const int sub = L >> 2;       // entry stripe 0..7
    float a0 = 0.f, a1 = 0.f, a2 = 0.f, a3 = 0.f;
    float a4 = 0.f, a5 = 0.f, a6 = 0.f, a7 = 0.f;
    #pragma unroll
    for (int i = 0; i < 8; ++i) {
        int2 d = ent[il][sub + 8 * i];
        float w = __int_as_float(d.y);
        uint4 v = *(const uint4*)(valb + (size_t)(unsigned)d.x + oct * 8);
        a0 = fmaf(w, bflo(v.x), a0); a1 = fmaf(w, bfhi(v.x), a1);
        a2 = fmaf(w, bflo(v.y), a2); a3 = fmaf(w, bfhi(v.y), a3);
        a4 = fmaf(w, bflo(v.z), a4); a5 = fmaf(w, bfhi(v.z), a5);
        a6 = fmaf(w, bflo(v.w), a6); a7 = fmaf(w, bfhi(v.w), a7);
    }
    #pragma unroll
    for (int mk = 4; mk <= 16; mk <<= 1) {
        a0 += __shfl_xor(a0, mk); a1 += __shfl_xor(a1, mk);
        a2 += __shfl_xor(a2, mk); a3 += __shfl_xor(a3, mk);
        a4 += __shfl_xor(a4, mk); a5 += __shfl_xor(a5, mk);
        a6 += __shfl_xor(a6, mk); a7 += __shfl_xor(a7, mk);
    }
    if (sub == 0) {
        uint4 o;
        o.x = pack2(a0, a1); o.y = pack2(a2, a3);
        o.z = pack2(a4, a5); o.w = pack2(a6, a7);
        *(uint4*)(out + (size_t)item * DHH + oct * 8) = o;
    }
}

// ---------------------------------------------------------------- residual + LN (+ bf16 copy, + optional q=bf16(out+pos))
__global__ __launch_bounds__(256) void resln_kernel(
    float* __restrict__ x, const float* __restrict__ r,
    const float* __restrict__ g, const float* __restrict__ bta,
    unsigned short* __restrict__ xb,
    const float* __restrict__ pos, unsigned short* __restrict__ qb)
{
    int row = blockIdx.x * 4 + (threadIdx.x >> 6);
    int lane = threadIdx.x & 63;
    if (row >= ROWS) return;
    float4 v  = *(const float4*)(x + (size_t)row * DD + lane * 4);
    float4 rr = *(const float4*)(r + (size_t)row * DD + lane * 4);
    v.x += rr.x; v.y += rr.y; v.z += rr.z; v.w += rr.w;
    float s  = v.x + v.y + v.z + v.w;
    float s2 = v.x * v.x + v.y * v.y + v.z * v.z + v.w * v.w;
    #pragma unroll
    for (int o = 1; o < 64; o <<= 1) {
        s  += __shfl_xor(s, o);
        s2 += __shfl_xor(s2, o);
    }
    float mean = s * (1.f / DD);
    float var  = s2 * (1.f / DD) - mean * mean;
    float inv  = rsqrtf(var + 1e-5f);
    float4 gg = *(const float4*)(g + lane * 4);
    float4 bb = *(const float4*)(bta + lane * 4);
    float4 o;
    o.x = (v.x - mean) * inv * gg.x + bb.x;
    o.y = (v.y - mean) * inv * gg.y + bb.y;
    o.z = (v.z - mean) * inv * gg.z + bb.z;
    o.w = (v.w - mean) * inv * gg.w + bb.w;
    *(float4*)(x + (size_t)row * DD + lane * 4) = o;
    uint2 ob;
    ob.x = pack2(o.x, o.y);
    ob.y = pack2(o.z, o.w);
    ((uint2*)(xb + (size_t)row * DD))[lane] = ob;
    if (qb) {
        float4 pv = *(const float4*)(pos + (size_t)row * DD + lane * 4);
        uint2 oq;
        oq.x = pack2(o.x + pv.x, o.y + pv.y);
        oq.y = pack2(o.z + pv.z, o.w + pv.w);
        ((uint2*)(qb + (size_t)row * DD))[lane] = oq;
    }
}

// ---------------------------------------------------------------- launch
extern "C" void kernel_launch(void* const* d_in, const int* in_sizes, int n_in,
                              void* d_out, int out_size, void* d_ws, size_t ws_size,
                              hipStream_t stream)
{
    const float* src    = (const float*)d_in[0];
    const float* pos    = (const float*)d_in[1];
    const float* vr     = (const float*)d_in[2];
    const float* W_off  = (const float*)d_in[3];
    const float* b_off  = (const float*)d_in[4];
    const float* W_attn = (const float*)d_in[5];
    const float* b_attn = (const float*)d_in[6];
    const float* W_val  = (const float*)d_in[7];
    const float* b_val  = (const float*)d_in[8];
    const float* W_out  = (const float*)d_in[9];
    const float* b_out  = (const float*)d_in[10];
    const float* ln1_g  = (const float*)d_in[11];
    const float* ln1_b  = (const float*)d_in[12];
    const float* W_ff1  = (const float*)d_in[13];
    const float* b_ff1  = (const float*)d_in[14];
    const float* W_ff2  = (const float*)d_in[15];
    const float* b_ff2  = (const float*)d_in[16];
    const float* ln2_g  = (const float*)d_in[17];
    const float* ln2_b  = (const float*)d_in[18];

    float* x = (float*)d_out;
    float* ws = (float*)d_ws;
    size_t o = 0;
    float* tmp     = ws + o; o += (size_t)ROWS * 256;
    float* ref     = ws + o; o += (size_t)ROWS * 8;
    float* bias_oa = ws + o; o += 3 * 384;

    unsigned short* ub = (unsigned short*)(ws + o);
    size_t uo = 0;
    unsigned short* oa      = ub + uo; uo += (size_t)ROWS * 384;
    unsigned short* q_bf    = ub + uo; uo += (size_t)ROWS * 256;
    unsigned short* x_bf    = ub + uo; uo += (size_t)ROWS * 256;
    unsigned short* samp_bf = ub + uo; uo += (size_t)ROWS * 256;
    unsigned short* val_bf  = ub + uo; uo += (size_t)ROWS * 256;
    unsigned short* h_bf    = ub + uo; uo += (size_t)ROWS * DFF_;
    unsigned short* WT_oa   = ub + uo; uo += (size_t)3 * 384 * 256;
    unsigned short* WT_val  = ub + uo; uo += (size_t)3 * 256 * 256;
    unsigned short* WT_out  = ub + uo; uo += (size_t)3 * 256 * 256;
    unsigned short* WT_ff1  = ub + uo; uo += (size_t)3 * 256 * 1024;
    unsigned short* WT_ff2  = ub + uo; uo += (size_t)3 * 1024 * 256;

    const int n8 = ROWS * DD / 8;

    convert_src_kernel<<<(n8 + 255) / 256, 256, 0, stream>>>(src, pos, x, x_bf, q_bf, n8);
    ref_points_kernel<<<(ROWS + 255) / 256, 256, 0, stream>>>(vr, ref);

    dim3 wtb(32, 8);
    wt_kernel<<<dim3(8,  8, 3), wtb, 0, stream>>>(W_off,  WT_oa,  256, 256,  384 * 256, 0);
    wt_kernel<<<dim3(8,  4, 3), wtb, 0, stream>>>(W_attn, WT_oa,  256, 128,  384 * 256, 256);
    wt_kernel<<<dim3(8,  8, 3), wtb, 0, stream>>>(W_val,  WT_val, 256, 256,  256 * 256, 0);
    wt_kernel<<<dim3(8,  8, 3), wtb, 0, stream>>>(W_out,  WT_out, 256, 256,  256 * 256, 0);
    wt_kernel<<<dim3(8, 32, 3), wtb, 0, stream>>>(W_ff1,  WT_ff1, 256, 1024, 256 * 1024, 0);
    wt_kernel<<<dim3(32, 8, 3), wtb, 0, stream>>>(W_ff2,  WT_ff2, 1024, 256, 1024 * 256, 0);
    bias_oa_kernel<<<(3 * 384 + 255) / 256, 256, 0, stream>>>(b_off, b_attn, bias_oa);

    dim3 g384(160, 3);        // BN=128 -> 480 blocks (94% fill)
    dim3 g256n64(160, 4);     // BN=64  -> 640 blocks (83% fill)
    dim3 g1024(160, 8);       // BN=128 -> 1280 blocks (99.7% fill)

    for (int l = 0; l < 3; ++l) {
        // [offs | attn logits] = q @ [W_off|W_attn] + bias  (bf16 out)
        gemm_bf16<128, 128, 2><<<g384, 256, 0, stream>>>(
            q_bf, WT_oa + (size_t)l * 384 * 256, bias_oa + (size_t)l * 384, oa,
            ROWS, 384, 256);
        // val (bf16 out)
        gemm_bf16<128, 64, 2><<<g256n64, 256, 0, stream>>>(
            x_bf, WT_val + (size_t)l * 65536, b_val + (size_t)l * 256, val_bf,
            ROWS, 256, 256);
        // deformable sampling (softmax fused)
        sample_kernel<<<ROWS * NHH / 8, 256, 0, stream>>>(
            val_bf, oa, ref, samp_bf);
        // att_out = samp @ W_out + b_out
        gemm_bf16<128, 64, 0><<<g256n64, 256, 0, stream>>>(
            samp_bf, WT_out + (size_t)l * 65536, b_out + (size_t)l * 256, tmp,
            ROWS, 256, 256);
        resln_kernel<<<(ROWS + 3) / 4, 256, 0, stream>>>(
            x, tmp, ln1_g + (size_t)l * 256, ln1_b + (size_t)l * 256, x_bf,
            nullptr, nullptr);
        gemm_bf16<128, 128, 1><<<g1024, 256, 0, stream>>>(
            x_bf, WT_ff1 + (size_t)l * 262144, b_ff1 + (size_t)l * 1024, h_bf,
            ROWS, 1024, 256);
        gemm_bf16<128, 64, 0><<<g256n64, 256, 0, stream>>>(
            h_bf, WT_ff2 + (size_t)l * 262144, b_ff2 + (size_t)l * 256, tmp,
            ROWS, 256, 1024);
        resln_kernel<<<(ROWS + 3) / 4, 256, 0, stream>>>(
            x, tmp, ln2_g + (size_t)l * 256, ln2_b + (size_t)l * 256, x_bf,
            (l < 2) ? pos : nullptr, (l < 2) ? q_bf : nullptr);
    }
}